// Round 1
// baseline (1048.609 us; speedup 1.0000x reference)
//
#include <hip/hip_runtime.h>

#define NN 50000
#define NE 800000
#define D 64
#define EPS 1e-5f

__device__ __forceinline__ float wave_sum64(float v) {
#pragma unroll
  for (int m = 1; m <= 32; m <<= 1) v += __shfl_xor(v, m, 64);
  return v;
}
__device__ __forceinline__ float group_sum16(float v) {
#pragma unroll
  for (int m = 1; m <= 8; m <<= 1) v += __shfl_xor(v, m, 64);
  return v;
}
__device__ __forceinline__ float silu_f(float v) { return v / (1.f + __expf(-v)); }
__device__ __forceinline__ float lrelu_f(float v) { return v >= 0.f ? v : 0.2f * v; }

// ---------- graph preprocessing (once per launch) ----------

__global__ void k_init(float* deg, int* cnt, float* scal, int n) {
  int i = blockIdx.x * blockDim.x + threadIdx.x;
  if (i < n) { deg[i] = 1.0f; cnt[i] = 0; }
  if (i == 0) { scal[0] = 0.f; }
}

__global__ void k_hist(const int* __restrict__ ei, const float* __restrict__ ew,
                       const float* __restrict__ ea, float* deg, int* cnt,
                       float* scal, int e_total) {
  int e = blockIdx.x * blockDim.x + threadIdx.x;
  float a = 0.f;
  if (e < e_total) {
    int dst = ei[e_total + e];
    atomicAdd(&deg[dst], ew[e]);
    atomicAdd(&cnt[dst], 1);
    a = ea[e];
  }
  a = wave_sum64(a);
  if ((threadIdx.x & 63) == 0) atomicAdd(&scal[0], a);
}

__global__ void k_scan(const int* __restrict__ cnt, int* row_start, int* fill, int n, int e_total) {
  __shared__ int sums[1024];
  int t = threadIdx.x;
  const int CH = (n + 1023) / 1024;
  int base = t * CH;
  int s = 0;
  for (int j = 0; j < CH; ++j) {
    int idx = base + j;
    if (idx < n) s += cnt[idx];
  }
  sums[t] = s;
  __syncthreads();
  for (int off = 1; off < 1024; off <<= 1) {
    int v = (t >= off) ? sums[t - off] : 0;
    __syncthreads();
    sums[t] += v;
    __syncthreads();
  }
  int run = (t == 0) ? 0 : sums[t - 1];
  for (int j = 0; j < CH; ++j) {
    int idx = base + j;
    if (idx < n) { row_start[idx] = run; fill[idx] = run; run += cnt[idx]; }
  }
  if (t == 1023) row_start[n] = sums[1023];
  (void)e_total;
}

__global__ void k_post(const float* __restrict__ deg, float* dinv, float* scal, int n, int e_total) {
  int i = blockIdx.x * blockDim.x + threadIdx.x;
  if (i < n) dinv[i] = rsqrtf(deg[i]);
  if (i == 0) scal[1] = scal[0] / (float)e_total;
}

__global__ void k_scatter(const int* __restrict__ ei, const float* __restrict__ ew,
                          const float* __restrict__ ea, int* fill,
                          int* sorted_src, float* sorted_w, float* sorted_ea, int e_total) {
  int e = blockIdx.x * blockDim.x + threadIdx.x;
  if (e >= e_total) return;
  int src = ei[e];
  int dst = ei[e_total + e];
  int slot = atomicAdd(&fill[dst], 1);
  sorted_src[slot] = src;
  sorted_w[slot] = ew[e];
  sorted_ea[slot] = ea[e];
}

// ---------- dense ops ----------

// out1 = x @ W1            (GCN h, no bias)
// out2 = x @ W2 + b2       (residual)
__global__ void k_dual_gemm(const float* __restrict__ x, const float* __restrict__ W1,
                            const float* __restrict__ W2, const float* __restrict__ b2,
                            float* __restrict__ out1, float* __restrict__ out2, int n) {
  int t = blockIdx.x * blockDim.x + threadIdx.x;
  int r = t >> 6, c = t & 63;
  if (r >= n) return;
  const float* xr = x + (size_t)r * D;
  float a1 = 0.f, a2 = 0.f;
#pragma unroll
  for (int k = 0; k < D; k += 4) {
    float4 xv = *(const float4*)(xr + k);
    a1 = fmaf(xv.x, W1[(k + 0) * D + c], a1); a2 = fmaf(xv.x, W2[(k + 0) * D + c], a2);
    a1 = fmaf(xv.y, W1[(k + 1) * D + c], a1); a2 = fmaf(xv.y, W2[(k + 1) * D + c], a2);
    a1 = fmaf(xv.z, W1[(k + 2) * D + c], a1); a2 = fmaf(xv.z, W2[(k + 2) * D + c], a2);
    a1 = fmaf(xv.w, W1[(k + 3) * D + c], a1); a2 = fmaf(xv.w, W2[(k + 3) * D + c], a2);
  }
  out1[(size_t)r * D + c] = a1;
  out2[(size_t)r * D + c] = a2 + b2[c];
}

// GCN aggregate + bias + silu + residual + LayerNorm -> x2. One wave per node.
__global__ void __launch_bounds__(256) k_gcn_agg(
    const float* __restrict__ h, const float* __restrict__ res,
    const float* __restrict__ dinv, const int* __restrict__ rs,
    const int* __restrict__ ssrc, const float* __restrict__ sw,
    const float* __restrict__ gb, const float* __restrict__ lg, const float* __restrict__ lb,
    float* __restrict__ x2, int n) {
  int i = (blockIdx.x * blockDim.x + threadIdx.x) >> 6;
  int c = threadIdx.x & 63;
  if (i >= n) return;
  float di = dinv[i];
  float acc = di * di * h[(size_t)i * D + c];  // self loop, w=1
  int k0 = rs[i], k1 = rs[i + 1];
  for (int k = k0; k < k1; ++k) {
    int s = ssrc[k];
    float nw = dinv[s] * sw[k] * di;
    acc = fmaf(nw, h[(size_t)s * D + c], acc);
  }
  float v = acc + gb[c];
  float x1 = silu_f(v) + res[(size_t)i * D + c];
  float mu = wave_sum64(x1) * (1.f / 64.f);
  float d = x1 - mu;
  float var = wave_sum64(d * d) * (1.f / 64.f);
  x2[(size_t)i * D + c] = d * rsqrtf(var + EPS) * lg[c] + lb[c];
}

// xl = x2 @ Wg (no bias); a_s/a_d head reductions. One wave per row.
__global__ void k_gat_node(const float* __restrict__ x2, const float* __restrict__ Wg,
                           const float* __restrict__ att_src, const float* __restrict__ att_dst,
                           float* __restrict__ xl, float* __restrict__ a_s, float* __restrict__ a_d,
                           int n) {
  int t = blockIdx.x * blockDim.x + threadIdx.x;
  int r = t >> 6, c = t & 63;
  if (r >= n) return;
  const float* xr = x2 + (size_t)r * D;
  float acc = 0.f;
#pragma unroll
  for (int k = 0; k < D; k += 4) {
    float4 xv = *(const float4*)(xr + k);
    acc = fmaf(xv.x, Wg[(k + 0) * D + c], acc);
    acc = fmaf(xv.y, Wg[(k + 1) * D + c], acc);
    acc = fmaf(xv.z, Wg[(k + 2) * D + c], acc);
    acc = fmaf(xv.w, Wg[(k + 3) * D + c], acc);
  }
  xl[(size_t)r * D + c] = acc;
  float vs = group_sum16(acc * att_src[c]);
  float vd = group_sum16(acc * att_dst[c]);
  if ((c & 15) == 0) {
    a_s[(size_t)r * 4 + (c >> 4)] = vs;
    a_d[(size_t)r * 4 + (c >> 4)] = vd;
  }
}

// GAT online-softmax aggregate + bias + silu + residual -> xout. One wave per node.
__global__ void __launch_bounds__(256) k_gat_agg(
    const float* __restrict__ xl, const float* __restrict__ x2,
    const float* __restrict__ a_s, const float* __restrict__ a_d,
    const int* __restrict__ rs, const int* __restrict__ ssrc, const float* __restrict__ sea,
    const float* __restrict__ We, const float* __restrict__ a_e, const float* __restrict__ scal,
    const float* __restrict__ bg, float* __restrict__ xout, int n) {
  int i = (blockIdx.x * blockDim.x + threadIdx.x) >> 6;
  int c = threadIdx.x & 63;
  if (i >= n) return;
  int hh = c >> 4;
  // weA[h] = sum_c We[h*16+cc]*att_e[h*16+cc]; butterfly leaves full group sum in all lanes
  float weA = group_sum16(We[c] * a_e[c]);
  float mean_attr = scal[1];
  float adi = a_d[(size_t)i * 4 + hh];
  float asi = a_s[(size_t)i * 4 + hh];
  // self loop: edge_attr = mean
  float alpha = lrelu_f(asi + adi + mean_attr * weA);
  float m_run = alpha;
  float s_run = 1.f;
  float acc = xl[(size_t)i * D + c];
  int k0 = rs[i], k1 = rs[i + 1];
  for (int k = k0; k < k1; ++k) {
    int s = ssrc[k];
    float ea = sea[k];
    float al = lrelu_f(a_s[(size_t)s * 4 + hh] + adi + ea * weA);
    float xv = xl[(size_t)s * D + c];
    float mn = fmaxf(m_run, al);
    float e0 = __expf(m_run - mn);
    float e1 = __expf(al - mn);
    s_run = fmaf(s_run, e0, e1);
    acc = fmaf(acc, e0, e1 * xv);
    m_run = mn;
  }
  float o = acc / (s_run + 1e-16f) + bg[c];
  float y = silu_f(o) + x2[(size_t)i * D + c];
  xout[(size_t)i * D + c] = y;
}

// ---------- launch ----------

extern "C" void kernel_launch(void* const* d_in, const int* in_sizes, int n_in,
                              void* d_out, int out_size, void* d_ws, size_t ws_size,
                              hipStream_t stream) {
  (void)in_sizes; (void)n_in; (void)out_size; (void)ws_size;
  const float* x  = (const float*)d_in[0];
  const int*   ei = (const int*)d_in[1];
  const float* ew = (const float*)d_in[2];
  const float* ea = (const float*)d_in[3];
  // per-layer params: 0 gcn_w,1 gcn_b,2 res_w,3 res_b,4 ln_g,5 ln_b,
  //                   6 gat_w,7 gat_b,8 att_src,9 att_dst,10 att_e,11 ew_w
  const float* P[2][12];
  for (int l = 0; l < 2; ++l)
    for (int j = 0; j < 12; ++j) P[l][j] = (const float*)d_in[4 + l * 12 + j];

  float* W = (float*)d_ws;
  const size_t o_deg  = 0;
  const size_t o_dinv = o_deg + NN;
  const size_t o_cnt  = o_dinv + NN;
  const size_t o_rs   = o_cnt + NN;          // NN+1 ints
  const size_t o_fill = o_rs + NN + 8;
  const size_t o_scal = o_fill + NN;         // 8 floats: [0]=attr_sum [1]=mean_attr
  const size_t o_ssrc = o_scal + 8;          // NE ints
  const size_t o_sw   = o_ssrc + NE;
  const size_t o_sea  = o_sw + NE;
  const size_t o_h    = o_sea + NE;
  const size_t o_res  = o_h + (size_t)NN * D;
  const size_t o_x2   = o_res + (size_t)NN * D;
  const size_t o_xl   = o_x2 + (size_t)NN * D;
  const size_t o_as   = o_xl + (size_t)NN * D;
  const size_t o_ad   = o_as + (size_t)NN * 4;
  const size_t o_xmid = o_ad + (size_t)NN * 4;

  float* deg  = W + o_deg;
  float* dinv = W + o_dinv;
  int*   cnt  = (int*)(W + o_cnt);
  int*   rs   = (int*)(W + o_rs);
  int*   fill = (int*)(W + o_fill);
  float* scal = W + o_scal;
  int*   ssrc = (int*)(W + o_ssrc);
  float* sw   = W + o_sw;
  float* sea  = W + o_sea;
  float* hb   = W + o_h;
  float* resb = W + o_res;
  float* x2b  = W + o_x2;
  float* xlb  = W + o_xl;
  float* asb  = W + o_as;
  float* adb  = W + o_ad;
  float* xmid = W + o_xmid;

  const int B = 256;
  const int gN  = (NN + B - 1) / B;
  const int gE  = (NE + B - 1) / B;
  const int gNW = (NN * D + B - 1) / B;  // one wave per node/row

  // graph prep (shared by both layers)
  k_init<<<gN, B, 0, stream>>>(deg, cnt, scal, NN);
  k_hist<<<gE, B, 0, stream>>>(ei, ew, ea, deg, cnt, scal, NE);
  k_scan<<<1, 1024, 0, stream>>>(cnt, rs, fill, NN, NE);
  k_post<<<gN, B, 0, stream>>>(deg, dinv, scal, NN, NE);
  k_scatter<<<gE, B, 0, stream>>>(ei, ew, ea, fill, ssrc, sw, sea, NE);

  const float* xin = x;
  for (int l = 0; l < 2; ++l) {
    float* xout = (l == 0) ? xmid : (float*)d_out;
    k_dual_gemm<<<gNW, B, 0, stream>>>(xin, P[l][0], P[l][2], P[l][3], hb, resb, NN);
    k_gcn_agg<<<gNW, B, 0, stream>>>(hb, resb, dinv, rs, ssrc, sw,
                                     P[l][1], P[l][4], P[l][5], x2b, NN);
    k_gat_node<<<gNW, B, 0, stream>>>(x2b, P[l][6], P[l][8], P[l][9], xlb, asb, adb, NN);
    k_gat_agg<<<gNW, B, 0, stream>>>(xlb, x2b, asb, adb, rs, ssrc, sea,
                                     P[l][11], P[l][10], scal, P[l][7], xout, NN);
    xin = xout;
  }
}

// Round 2
// 684.199 us; speedup vs baseline: 1.5326x; 1.5326x over previous
//
#include <hip/hip_runtime.h>

#define NN 50000
#define NE 800000
#define D 64
#define EPS 1e-5f
#define PAD 16  // ints per counter slot -> one 64B line each

__device__ __forceinline__ float wave_sum64(float v) {
#pragma unroll
  for (int m = 1; m <= 32; m <<= 1) v += __shfl_xor(v, m, 64);
  return v;
}
__device__ __forceinline__ float group_sum16(float v) {
#pragma unroll
  for (int m = 1; m <= 8; m <<= 1) v += __shfl_xor(v, m, 64);
  return v;
}
__device__ __forceinline__ float silu_f(float v) { return v / (1.f + __expf(-v)); }
__device__ __forceinline__ float lrelu_f(float v) { return v >= 0.f ? v : 0.2f * v; }

// ---------- graph preprocessing ----------

// count in-degree (padded counters), partial-sum edge_attr into 64 padded slots
__global__ void k_hist(const int* __restrict__ ei, const float* __restrict__ ea,
                       int* __restrict__ cnt_p, float* __restrict__ scal) {
  int e = blockIdx.x * blockDim.x + threadIdx.x;
  float a = 0.f;
  if (e < NE) {
    int dst = ei[NE + e];
    atomicAdd(&cnt_p[(size_t)dst * PAD], 1);
    a = ea[e];
  }
  a = wave_sum64(a);
  if ((threadIdx.x & 63) == 0) {
    int slot = (blockIdx.x * 4 + (threadIdx.x >> 6)) & 63;
    atomicAdd(&scal[(size_t)slot * 16], a);
  }
}

__global__ void k_scanA(const int* __restrict__ cnt_p, int* __restrict__ rs,
                        int* __restrict__ bsum) {
  __shared__ int sm[256];
  int j = threadIdx.x, i = blockIdx.x * 256 + j;
  int v = (i < NN) ? cnt_p[(size_t)i * PAD] : 0;
  sm[j] = v;
  __syncthreads();
  for (int off = 1; off < 256; off <<= 1) {
    int t = (j >= off) ? sm[j - off] : 0;
    __syncthreads();
    sm[j] += t;
    __syncthreads();
  }
  if (i < NN) rs[i] = sm[j] - v;  // block-local exclusive
  if (j == 255) bsum[blockIdx.x] = sm[255];
}

__global__ void k_scanB(const int* __restrict__ bsum, int* __restrict__ boff) {
  __shared__ int sm[256];
  int j = threadIdx.x;
  const int nb = (NN + 255) / 256;
  int v = (j < nb) ? bsum[j] : 0;
  sm[j] = v;
  __syncthreads();
  for (int off = 1; off < 256; off <<= 1) {
    int t = (j >= off) ? sm[j - off] : 0;
    __syncthreads();
    sm[j] += t;
    __syncthreads();
  }
  if (j < nb) boff[j] = sm[j] - v;
}

__global__ void k_scanC(int* __restrict__ rs, const int* __restrict__ boff,
                        int* __restrict__ fill_p) {
  int i = blockIdx.x * blockDim.x + threadIdx.x;
  if (i < NN) {
    int r = rs[i] + boff[i >> 8];
    rs[i] = r;
    fill_p[(size_t)i * PAD] = r;
  }
  if (i == 0) rs[NN] = NE;
}

// scatter edges into CSR slots, packed float4: (src, w, ea, dst)
__global__ void k_scatter(const int* __restrict__ ei, const float* __restrict__ ew,
                          const float* __restrict__ ea, int* __restrict__ fill_p,
                          float4* __restrict__ edges) {
  int e = blockIdx.x * blockDim.x + threadIdx.x;
  if (e >= NE) return;
  int src = ei[e];
  int dst = ei[NE + e];
  int slot = atomicAdd(&fill_p[(size_t)dst * PAD], 1);
  float4 f;
  f.x = __int_as_float(src);
  f.y = ew[e];
  f.z = ea[e];
  f.w = __int_as_float(dst);
  edges[slot] = f;
}

// deg -> dinv per node; thread 0 finalizes mean edge_attr
__global__ void k_deg(const float4* __restrict__ edges, const int* __restrict__ rs,
                      float* __restrict__ dinv, float* __restrict__ scal) {
  int i = blockIdx.x * blockDim.x + threadIdx.x;
  if (i < NN) {
    float s = 1.f;  // self loop weight
    int k1 = rs[i + 1];
    for (int k = rs[i]; k < k1; ++k) s += edges[k].y;
    dinv[i] = rsqrtf(s);
  }
  if (i == 0) {
    float t = 0.f;
    for (int j = 0; j < 64; ++j) t += scal[(size_t)j * 16];
    scal[1] = t / (float)NE;
  }
}

// pre-normalize GCN edge weights: w *= dinv[src]*dinv[dst]
__global__ void k_norm(float4* __restrict__ edges, const float* __restrict__ dinv) {
  int e = blockIdx.x * blockDim.x + threadIdx.x;
  if (e >= NE) return;
  float4 f = edges[e];
  int src = __float_as_int(f.x), dst = __float_as_int(f.w);
  f.y *= dinv[src] * dinv[dst];
  edges[e] = f;
}

// ---------- dense ops ----------

// out1 = x @ W1 ; out2 = x @ W2 + b2.  NOTE: x may alias out1 (layer 2) -> no restrict.
__global__ void k_dual_gemm(const float* x, const float* __restrict__ W1,
                            const float* __restrict__ W2, const float* __restrict__ b2,
                            float* out1, float* __restrict__ out2, int n) {
  int t = blockIdx.x * blockDim.x + threadIdx.x;
  int r = t >> 6, c = t & 63;
  if (r >= n) return;
  const float* xr = x + (size_t)r * D;
  float a1 = 0.f, a2 = 0.f;
#pragma unroll
  for (int k = 0; k < D; k += 4) {
    float4 xv = *(const float4*)(xr + k);
    a1 = fmaf(xv.x, W1[(k + 0) * D + c], a1); a2 = fmaf(xv.x, W2[(k + 0) * D + c], a2);
    a1 = fmaf(xv.y, W1[(k + 1) * D + c], a1); a2 = fmaf(xv.y, W2[(k + 1) * D + c], a2);
    a1 = fmaf(xv.z, W1[(k + 2) * D + c], a1); a2 = fmaf(xv.z, W2[(k + 2) * D + c], a2);
    a1 = fmaf(xv.w, W1[(k + 3) * D + c], a1); a2 = fmaf(xv.w, W2[(k + 3) * D + c], a2);
  }
  out1[(size_t)r * D + c] = a1;
  out2[(size_t)r * D + c] = a2 + b2[c];
}

// GCN aggregate + bias + silu + residual + LayerNorm. One wave per node.
__global__ void __launch_bounds__(256) k_gcn_agg(
    const float* __restrict__ h, const float* __restrict__ res,
    const float* __restrict__ dinv, const int* __restrict__ rs,
    const float4* __restrict__ edges,
    const float* __restrict__ gb, const float* __restrict__ lg, const float* __restrict__ lb,
    float* __restrict__ x2, int n) {
  int i = (blockIdx.x * blockDim.x + threadIdx.x) >> 6;
  int c = threadIdx.x & 63;
  if (i >= n) return;
  float di = dinv[i];
  float acc = di * di * h[(size_t)i * D + c];  // self loop
  int k0 = rs[i], k1 = rs[i + 1];
  int k = k0;
  for (; k + 4 <= k1; k += 4) {
    float4 e0 = edges[k], e1 = edges[k + 1], e2 = edges[k + 2], e3 = edges[k + 3];
    int s0 = __float_as_int(e0.x), s1 = __float_as_int(e1.x);
    int s2 = __float_as_int(e2.x), s3 = __float_as_int(e3.x);
    float h0 = h[(size_t)s0 * D + c], h1 = h[(size_t)s1 * D + c];
    float h2 = h[(size_t)s2 * D + c], h3 = h[(size_t)s3 * D + c];
    acc = fmaf(e0.y, h0, acc);
    acc = fmaf(e1.y, h1, acc);
    acc = fmaf(e2.y, h2, acc);
    acc = fmaf(e3.y, h3, acc);
  }
  for (; k < k1; ++k) {
    float4 e = edges[k];
    acc = fmaf(e.y, h[(size_t)__float_as_int(e.x) * D + c], acc);
  }
  float v = acc + gb[c];
  float x1 = silu_f(v) + res[(size_t)i * D + c];
  float mu = wave_sum64(x1) * (1.f / 64.f);
  float d = x1 - mu;
  float var = wave_sum64(d * d) * (1.f / 64.f);
  x2[(size_t)i * D + c] = d * rsqrtf(var + EPS) * lg[c] + lb[c];
}

// xl = x2 @ Wg ; per-head a_s, a_d. One wave per row.
__global__ void k_gat_node(const float* __restrict__ x2, const float* __restrict__ Wg,
                           const float* __restrict__ att_src, const float* __restrict__ att_dst,
                           float* __restrict__ xl, float* __restrict__ a_s, float* __restrict__ a_d,
                           int n) {
  int t = blockIdx.x * blockDim.x + threadIdx.x;
  int r = t >> 6, c = t & 63;
  if (r >= n) return;
  const float* xr = x2 + (size_t)r * D;
  float acc = 0.f;
#pragma unroll
  for (int k = 0; k < D; k += 4) {
    float4 xv = *(const float4*)(xr + k);
    acc = fmaf(xv.x, Wg[(k + 0) * D + c], acc);
    acc = fmaf(xv.y, Wg[(k + 1) * D + c], acc);
    acc = fmaf(xv.z, Wg[(k + 2) * D + c], acc);
    acc = fmaf(xv.w, Wg[(k + 3) * D + c], acc);
  }
  xl[(size_t)r * D + c] = acc;
  float vs = group_sum16(acc * att_src[c]);
  float vd = group_sum16(acc * att_dst[c]);
  if ((c & 15) == 0) {
    a_s[(size_t)r * 4 + (c >> 4)] = vs;
    a_d[(size_t)r * 4 + (c >> 4)] = vd;
  }
}

// GAT online-softmax aggregate + bias + silu + residual. One wave per node.
__global__ void __launch_bounds__(256) k_gat_agg(
    const float* __restrict__ xl, const float* __restrict__ x2,
    const float* __restrict__ a_s, const float* __restrict__ a_d,
    const int* __restrict__ rs, const float4* __restrict__ edges,
    const float* __restrict__ We, const float* __restrict__ a_e, const float* __restrict__ scal,
    const float* __restrict__ bg, float* xout, int n) {
  int i = (blockIdx.x * blockDim.x + threadIdx.x) >> 6;
  int c = threadIdx.x & 63;
  if (i >= n) return;
  int hh = c >> 4;
  float weA = group_sum16(We[c] * a_e[c]);
  float mean_attr = scal[1];
  float adi = a_d[(size_t)i * 4 + hh];
  float asi = a_s[(size_t)i * 4 + hh];
  float m_run = lrelu_f(asi + adi + mean_attr * weA);  // self loop
  float s_run = 1.f;
  float acc = xl[(size_t)i * D + c];
  int k0 = rs[i], k1 = rs[i + 1];
  int k = k0;
  for (; k + 2 <= k1; k += 2) {
    float4 e0 = edges[k], e1 = edges[k + 1];
    int s0 = __float_as_int(e0.x), s1 = __float_as_int(e1.x);
    float as0 = a_s[(size_t)s0 * 4 + hh], as1 = a_s[(size_t)s1 * 4 + hh];
    float x0 = xl[(size_t)s0 * D + c], x1 = xl[(size_t)s1 * D + c];
    float al0 = lrelu_f(as0 + adi + e0.z * weA);
    float al1 = lrelu_f(as1 + adi + e1.z * weA);
    float mn = fmaxf(m_run, al0);
    float p0 = __expf(m_run - mn), p1 = __expf(al0 - mn);
    s_run = fmaf(s_run, p0, p1);
    acc = fmaf(acc, p0, p1 * x0);
    m_run = mn;
    mn = fmaxf(m_run, al1);
    p0 = __expf(m_run - mn); p1 = __expf(al1 - mn);
    s_run = fmaf(s_run, p0, p1);
    acc = fmaf(acc, p0, p1 * x1);
    m_run = mn;
  }
  for (; k < k1; ++k) {
    float4 e = edges[k];
    int s = __float_as_int(e.x);
    float al = lrelu_f(a_s[(size_t)s * 4 + hh] + adi + e.z * weA);
    float xv = xl[(size_t)s * D + c];
    float mn = fmaxf(m_run, al);
    float p0 = __expf(m_run - mn), p1 = __expf(al - mn);
    s_run = fmaf(s_run, p0, p1);
    acc = fmaf(acc, p0, p1 * xv);
    m_run = mn;
  }
  float o = acc / (s_run + 1e-16f) + bg[c];
  xout[(size_t)i * D + c] = silu_f(o) + x2[(size_t)i * D + c];
}

// ---------- launch ----------

extern "C" void kernel_launch(void* const* d_in, const int* in_sizes, int n_in,
                              void* d_out, int out_size, void* d_ws, size_t ws_size,
                              hipStream_t stream) {
  (void)in_sizes; (void)n_in; (void)out_size; (void)ws_size;
  const float* x  = (const float*)d_in[0];
  const int*   ei = (const int*)d_in[1];
  const float* ew = (const float*)d_in[2];
  const float* ea = (const float*)d_in[3];
  const float* P[2][12];
  for (int l = 0; l < 2; ++l)
    for (int j = 0; j < 12; ++j) P[l][j] = (const float*)d_in[4 + l * 12 + j];

  float* W = (float*)d_ws;
  // layout (floats)
  const size_t o_rs    = 0;                      // NN+1 ints (reserve NN+16)
  const size_t o_dinv  = o_rs + NN + 16;         // NN
  const size_t o_scal  = o_dinv + NN;            // 64*16
  const size_t o_bsum  = o_scal + 1024;          // 256 ints
  const size_t o_boff  = o_bsum + 256;           // 256 ints
  const size_t o_edges = o_boff + 256;           // NE*4 (float4-aligned: offset %4==0)
  const size_t o_h     = o_edges + (size_t)NE * 4;  // NN*D  (aliased: cnt_p during prep, xmid after L1)
  const size_t o_res   = o_h + (size_t)NN * D;      // NN*D  (aliased: fill_p during prep)
  const size_t o_x2    = o_res + (size_t)NN * D;
  const size_t o_xl    = o_x2 + (size_t)NN * D;
  const size_t o_as    = o_xl + (size_t)NN * D;     // NN*4
  const size_t o_ad    = o_as + (size_t)NN * 4;     // NN*4

  int*    rs    = (int*)(W + o_rs);
  float*  dinv  = W + o_dinv;
  float*  scal  = W + o_scal;
  int*    bsum  = (int*)(W + o_bsum);
  int*    boff  = (int*)(W + o_boff);
  float4* edges = (float4*)(W + o_edges);
  float*  hb    = W + o_h;
  float*  resb  = W + o_res;
  float*  x2b   = W + o_x2;
  float*  xlb   = W + o_xl;
  float*  asb   = W + o_as;
  float*  adb   = W + o_ad;
  int*    cnt_p  = (int*)hb;    // prep-phase alias
  int*    fill_p = (int*)resb;  // prep-phase alias
  float*  xmid   = hb;          // layer-1 output alias (hb dead by then)

  const int B = 256;
  const int gN  = (NN + B - 1) / B;            // 196
  const int gE  = (NE + B - 1) / B;            // 3125
  const int gNW = (NN * D + B - 1) / B;        // wave per node

  hipMemsetAsync(cnt_p, 0, (size_t)NN * PAD * sizeof(int), stream);
  hipMemsetAsync(scal, 0, 1024 * sizeof(float), stream);
  k_hist<<<gE, B, 0, stream>>>(ei, ea, cnt_p, scal);
  k_scanA<<<gN, 256, 0, stream>>>(cnt_p, rs, bsum);
  k_scanB<<<1, 256, 0, stream>>>(bsum, boff);
  k_scanC<<<gN, B, 0, stream>>>(rs, boff, fill_p);
  k_scatter<<<gE, B, 0, stream>>>(ei, ew, ea, fill_p, edges);
  k_deg<<<gN, B, 0, stream>>>(edges, rs, dinv, scal);
  k_norm<<<gE, B, 0, stream>>>(edges, dinv);

  const float* xin = x;
  for (int l = 0; l < 2; ++l) {
    float* xout = (l == 0) ? xmid : (float*)d_out;
    k_dual_gemm<<<gNW, B, 0, stream>>>(xin, P[l][0], P[l][2], P[l][3], hb, resb, NN);
    k_gcn_agg<<<gNW, B, 0, stream>>>(hb, resb, dinv, rs, edges,
                                     P[l][1], P[l][4], P[l][5], x2b, NN);
    k_gat_node<<<gNW, B, 0, stream>>>(x2b, P[l][6], P[l][8], P[l][9], xlb, asb, adb, NN);
    k_gat_agg<<<gNW, B, 0, stream>>>(xlb, x2b, asb, adb, rs, edges,
                                     P[l][11], P[l][10], scal, P[l][7], xout, NN);
    xin = xout;
  }
}

// Round 3
// 585.753 us; speedup vs baseline: 1.7902x; 1.1681x over previous
//
#include <hip/hip_runtime.h>

#define NN 50000
#define NE 800000
#define D 64
#define EPS 1e-5f
#define PAD 16  // ints per counter slot -> one 64B line each
#define RB 8    // rows per wave in GEMM kernels (8 | 50000)

__device__ __forceinline__ float wave_sum64(float v) {
#pragma unroll
  for (int m = 1; m <= 32; m <<= 1) v += __shfl_xor(v, m, 64);
  return v;
}
__device__ __forceinline__ float group_sum16(float v) {
#pragma unroll
  for (int m = 1; m <= 8; m <<= 1) v += __shfl_xor(v, m, 64);
  return v;
}
__device__ __forceinline__ float silu_f(float v) { return v / (1.f + __expf(-v)); }
__device__ __forceinline__ float lrelu_f(float v) { return v >= 0.f ? v : 0.2f * v; }

// ---------- graph preprocessing ----------

__global__ void k_hist(const int* __restrict__ ei, const float* __restrict__ ea,
                       int* __restrict__ cnt_p, float* __restrict__ scal) {
  int e = blockIdx.x * blockDim.x + threadIdx.x;
  float a = 0.f;
  if (e < NE) {
    int dst = ei[NE + e];
    atomicAdd(&cnt_p[(size_t)dst * PAD], 1);
    a = ea[e];
  }
  a = wave_sum64(a);
  if ((threadIdx.x & 63) == 0) {
    int slot = (blockIdx.x * 4 + (threadIdx.x >> 6)) & 63;
    atomicAdd(&scal[(size_t)slot * 16], a);
  }
}

__global__ void k_scanA(const int* __restrict__ cnt_p, int* __restrict__ rs,
                        int* __restrict__ bsum) {
  __shared__ int sm[256];
  int j = threadIdx.x, i = blockIdx.x * 256 + j;
  int v = (i < NN) ? cnt_p[(size_t)i * PAD] : 0;
  sm[j] = v;
  __syncthreads();
  for (int off = 1; off < 256; off <<= 1) {
    int t = (j >= off) ? sm[j - off] : 0;
    __syncthreads();
    sm[j] += t;
    __syncthreads();
  }
  if (i < NN) rs[i] = sm[j] - v;
  if (j == 255) bsum[blockIdx.x] = sm[255];
}

__global__ void k_scanB(const int* __restrict__ bsum, int* __restrict__ boff) {
  __shared__ int sm[256];
  int j = threadIdx.x;
  const int nb = (NN + 255) / 256;
  int v = (j < nb) ? bsum[j] : 0;
  sm[j] = v;
  __syncthreads();
  for (int off = 1; off < 256; off <<= 1) {
    int t = (j >= off) ? sm[j - off] : 0;
    __syncthreads();
    sm[j] += t;
    __syncthreads();
  }
  if (j < nb) boff[j] = sm[j] - v;
}

__global__ void k_scanC(int* __restrict__ rs, const int* __restrict__ boff,
                        int* __restrict__ fill_p) {
  int i = blockIdx.x * blockDim.x + threadIdx.x;
  if (i < NN) {
    int r = rs[i] + boff[i >> 8];
    rs[i] = r;
    fill_p[(size_t)i * PAD] = r;
  }
  if (i == 0) rs[NN] = NE;
}

__global__ void k_scatter(const int* __restrict__ ei, const float* __restrict__ ew,
                          const float* __restrict__ ea, int* __restrict__ fill_p,
                          float4* __restrict__ edges) {
  int e = blockIdx.x * blockDim.x + threadIdx.x;
  if (e >= NE) return;
  int src = ei[e];
  int dst = ei[NE + e];
  int slot = atomicAdd(&fill_p[(size_t)dst * PAD], 1);
  float4 f;
  f.x = __int_as_float(src);
  f.y = ew[e];
  f.z = ea[e];
  f.w = __int_as_float(dst);
  edges[slot] = f;
}

__global__ void k_deg(const float4* __restrict__ edges, const int* __restrict__ rs,
                      float* __restrict__ dinv, float* __restrict__ scal) {
  int i = blockIdx.x * blockDim.x + threadIdx.x;
  if (i < NN) {
    float s = 1.f;
    int k1 = rs[i + 1];
    for (int k = rs[i]; k < k1; ++k) s += edges[k].y;
    dinv[i] = rsqrtf(s);
  }
  if (i == 0) {
    float t = 0.f;
    for (int j = 0; j < 64; ++j) t += scal[(size_t)j * 16];
    scal[1] = t / (float)NE;
  }
}

__global__ void k_norm(float4* __restrict__ edges, const float* __restrict__ dinv) {
  int e = blockIdx.x * blockDim.x + threadIdx.x;
  if (e >= NE) return;
  float4 f = edges[e];
  int src = __float_as_int(f.x), dst = __float_as_int(f.w);
  f.y *= dinv[src] * dinv[dst];
  edges[e] = f;
}

// ---------- dense ops (8 rows per wave: amortize weight loads over rows) ----------

// out1 = x @ W1 ; out2 = x @ W2 + b2.  x may alias out1 (layer 2): each wave
// reads only its own rows before writing them -> safe.
__global__ void __launch_bounds__(256) k_dual_gemm(
    const float* x, const float* __restrict__ W1,
    const float* __restrict__ W2, const float* __restrict__ b2,
    float* out1, float* __restrict__ out2, int n) {
  int wv = (blockIdx.x * blockDim.x + threadIdx.x) >> 6;
  int c = threadIdx.x & 63;
  int r0 = wv * RB;
  if (r0 >= n) return;
  const float* xr = x + (size_t)r0 * D;
  float a1[RB] = {0.f, 0.f, 0.f, 0.f, 0.f, 0.f, 0.f, 0.f};
  float a2[RB] = {0.f, 0.f, 0.f, 0.f, 0.f, 0.f, 0.f, 0.f};
#pragma unroll 2
  for (int k = 0; k < D; k += 4) {
    float w10 = W1[(k + 0) * D + c], w11 = W1[(k + 1) * D + c];
    float w12 = W1[(k + 2) * D + c], w13 = W1[(k + 3) * D + c];
    float w20 = W2[(k + 0) * D + c], w21 = W2[(k + 1) * D + c];
    float w22 = W2[(k + 2) * D + c], w23 = W2[(k + 3) * D + c];
#pragma unroll
    for (int r = 0; r < RB; ++r) {
      float4 xv = *(const float4*)(xr + (size_t)r * D + k);
      a1[r] = fmaf(xv.x, w10, a1[r]); a2[r] = fmaf(xv.x, w20, a2[r]);
      a1[r] = fmaf(xv.y, w11, a1[r]); a2[r] = fmaf(xv.y, w21, a2[r]);
      a1[r] = fmaf(xv.z, w12, a1[r]); a2[r] = fmaf(xv.z, w22, a2[r]);
      a1[r] = fmaf(xv.w, w13, a1[r]); a2[r] = fmaf(xv.w, w23, a2[r]);
    }
  }
  float bb = b2[c];
#pragma unroll
  for (int r = 0; r < RB; ++r) {
    out1[(size_t)(r0 + r) * D + c] = a1[r];
    out2[(size_t)(r0 + r) * D + c] = a2[r] + bb;
  }
}

// xl = x2 @ Wg ; per-head a_s, a_d. 8 rows per wave.
__global__ void __launch_bounds__(256) k_gat_node(
    const float* __restrict__ x2, const float* __restrict__ Wg,
    const float* __restrict__ att_src, const float* __restrict__ att_dst,
    float* __restrict__ xl, float* __restrict__ a_s, float* __restrict__ a_d,
    int n) {
  int wv = (blockIdx.x * blockDim.x + threadIdx.x) >> 6;
  int c = threadIdx.x & 63;
  int r0 = wv * RB;
  if (r0 >= n) return;
  const float* xr = x2 + (size_t)r0 * D;
  float acc[RB] = {0.f, 0.f, 0.f, 0.f, 0.f, 0.f, 0.f, 0.f};
#pragma unroll 2
  for (int k = 0; k < D; k += 4) {
    float w0 = Wg[(k + 0) * D + c], w1 = Wg[(k + 1) * D + c];
    float w2 = Wg[(k + 2) * D + c], w3 = Wg[(k + 3) * D + c];
#pragma unroll
    for (int r = 0; r < RB; ++r) {
      float4 xv = *(const float4*)(xr + (size_t)r * D + k);
      acc[r] = fmaf(xv.x, w0, acc[r]);
      acc[r] = fmaf(xv.y, w1, acc[r]);
      acc[r] = fmaf(xv.z, w2, acc[r]);
      acc[r] = fmaf(xv.w, w3, acc[r]);
    }
  }
  float asv = att_src[c], adv = att_dst[c];
#pragma unroll
  for (int r = 0; r < RB; ++r) {
    xl[(size_t)(r0 + r) * D + c] = acc[r];
    float vs = group_sum16(acc[r] * asv);
    float vd = group_sum16(acc[r] * adv);
    if ((c & 15) == 0) {
      a_s[(size_t)(r0 + r) * 4 + (c >> 4)] = vs;
      a_d[(size_t)(r0 + r) * 4 + (c >> 4)] = vd;
    }
  }
}

// GCN aggregate + bias + silu + residual + LayerNorm. One wave per node.
__global__ void __launch_bounds__(256) k_gcn_agg(
    const float* __restrict__ h, const float* __restrict__ res,
    const float* __restrict__ dinv, const int* __restrict__ rs,
    const float4* __restrict__ edges,
    const float* __restrict__ gb, const float* __restrict__ lg, const float* __restrict__ lb,
    float* __restrict__ x2, int n) {
  int i = (blockIdx.x * blockDim.x + threadIdx.x) >> 6;
  int c = threadIdx.x & 63;
  if (i >= n) return;
  float di = dinv[i];
  float acc = di * di * h[(size_t)i * D + c];
  int k0 = rs[i], k1 = rs[i + 1];
  int k = k0;
  for (; k + 4 <= k1; k += 4) {
    float4 e0 = edges[k], e1 = edges[k + 1], e2 = edges[k + 2], e3 = edges[k + 3];
    int s0 = __float_as_int(e0.x), s1 = __float_as_int(e1.x);
    int s2 = __float_as_int(e2.x), s3 = __float_as_int(e3.x);
    float h0 = h[(size_t)s0 * D + c], h1 = h[(size_t)s1 * D + c];
    float h2 = h[(size_t)s2 * D + c], h3 = h[(size_t)s3 * D + c];
    acc = fmaf(e0.y, h0, acc);
    acc = fmaf(e1.y, h1, acc);
    acc = fmaf(e2.y, h2, acc);
    acc = fmaf(e3.y, h3, acc);
  }
  for (; k < k1; ++k) {
    float4 e = edges[k];
    acc = fmaf(e.y, h[(size_t)__float_as_int(e.x) * D + c], acc);
  }
  float v = acc + gb[c];
  float x1 = silu_f(v) + res[(size_t)i * D + c];
  float mu = wave_sum64(x1) * (1.f / 64.f);
  float d = x1 - mu;
  float var = wave_sum64(d * d) * (1.f / 64.f);
  x2[(size_t)i * D + c] = d * rsqrtf(var + EPS) * lg[c] + lb[c];
}

// GAT online-softmax aggregate + bias + silu + residual. One wave per node.
__global__ void __launch_bounds__(256) k_gat_agg(
    const float* __restrict__ xl, const float* __restrict__ x2,
    const float* __restrict__ a_s, const float* __restrict__ a_d,
    const int* __restrict__ rs, const float4* __restrict__ edges,
    const float* __restrict__ We, const float* __restrict__ a_e, const float* __restrict__ scal,
    const float* __restrict__ bg, float* xout, int n) {
  int i = (blockIdx.x * blockDim.x + threadIdx.x) >> 6;
  int c = threadIdx.x & 63;
  if (i >= n) return;
  int hh = c >> 4;
  float weA = group_sum16(We[c] * a_e[c]);
  float mean_attr = scal[1];
  float adi = a_d[(size_t)i * 4 + hh];
  float asi = a_s[(size_t)i * 4 + hh];
  float m_run = lrelu_f(asi + adi + mean_attr * weA);
  float s_run = 1.f;
  float acc = xl[(size_t)i * D + c];
  int k0 = rs[i], k1 = rs[i + 1];
  int k = k0;
  for (; k + 2 <= k1; k += 2) {
    float4 e0 = edges[k], e1 = edges[k + 1];
    int s0 = __float_as_int(e0.x), s1 = __float_as_int(e1.x);
    float as0 = a_s[(size_t)s0 * 4 + hh], as1 = a_s[(size_t)s1 * 4 + hh];
    float x0 = xl[(size_t)s0 * D + c], x1 = xl[(size_t)s1 * D + c];
    float al0 = lrelu_f(as0 + adi + e0.z * weA);
    float al1 = lrelu_f(as1 + adi + e1.z * weA);
    float mn = fmaxf(m_run, al0);
    float p0 = __expf(m_run - mn), p1 = __expf(al0 - mn);
    s_run = fmaf(s_run, p0, p1);
    acc = fmaf(acc, p0, p1 * x0);
    m_run = mn;
    mn = fmaxf(m_run, al1);
    p0 = __expf(m_run - mn); p1 = __expf(al1 - mn);
    s_run = fmaf(s_run, p0, p1);
    acc = fmaf(acc, p0, p1 * x1);
    m_run = mn;
  }
  for (; k < k1; ++k) {
    float4 e = edges[k];
    int s = __float_as_int(e.x);
    float al = lrelu_f(a_s[(size_t)s * 4 + hh] + adi + e.z * weA);
    float xv = xl[(size_t)s * D + c];
    float mn = fmaxf(m_run, al);
    float p0 = __expf(m_run - mn), p1 = __expf(al - mn);
    s_run = fmaf(s_run, p0, p1);
    acc = fmaf(acc, p0, p1 * xv);
    m_run = mn;
  }
  float o = acc / (s_run + 1e-16f) + bg[c];
  xout[(size_t)i * D + c] = silu_f(o) + x2[(size_t)i * D + c];
}

// ---------- launch ----------

extern "C" void kernel_launch(void* const* d_in, const int* in_sizes, int n_in,
                              void* d_out, int out_size, void* d_ws, size_t ws_size,
                              hipStream_t stream) {
  (void)in_sizes; (void)n_in; (void)out_size; (void)ws_size;
  const float* x  = (const float*)d_in[0];
  const int*   ei = (const int*)d_in[1];
  const float* ew = (const float*)d_in[2];
  const float* ea = (const float*)d_in[3];
  const float* P[2][12];
  for (int l = 0; l < 2; ++l)
    for (int j = 0; j < 12; ++j) P[l][j] = (const float*)d_in[4 + l * 12 + j];

  float* W = (float*)d_ws;
  const size_t o_rs    = 0;
  const size_t o_dinv  = o_rs + NN + 16;
  const size_t o_scal  = o_dinv + NN;
  const size_t o_bsum  = o_scal + 1024;
  const size_t o_boff  = o_bsum + 256;
  const size_t o_edges = o_boff + 256;
  const size_t o_h     = o_edges + (size_t)NE * 4;
  const size_t o_res   = o_h + (size_t)NN * D;
  const size_t o_x2    = o_res + (size_t)NN * D;
  const size_t o_xl    = o_x2 + (size_t)NN * D;
  const size_t o_as    = o_xl + (size_t)NN * D;
  const size_t o_ad    = o_as + (size_t)NN * 4;

  int*    rs    = (int*)(W + o_rs);
  float*  dinv  = W + o_dinv;
  float*  scal  = W + o_scal;
  int*    bsum  = (int*)(W + o_bsum);
  int*    boff  = (int*)(W + o_boff);
  float4* edges = (float4*)(W + o_edges);
  float*  hb    = W + o_h;
  float*  resb  = W + o_res;
  float*  x2b   = W + o_x2;
  float*  xlb   = W + o_xl;
  float*  asb   = W + o_as;
  float*  adb   = W + o_ad;
  int*    cnt_p  = (int*)hb;
  int*    fill_p = (int*)resb;
  float*  xmid   = hb;

  const int B = 256;
  const int gN  = (NN + B - 1) / B;
  const int gE  = (NE + B - 1) / B;
  const int gNW = (NN * D + B - 1) / B;                 // one wave per node
  const int gRB = ((NN + RB - 1) / RB * 64 + B - 1) / B; // one wave per RB rows

  hipMemsetAsync(cnt_p, 0, (size_t)NN * PAD * sizeof(int), stream);
  hipMemsetAsync(scal, 0, 1024 * sizeof(float), stream);
  k_hist<<<gE, B, 0, stream>>>(ei, ea, cnt_p, scal);
  k_scanA<<<gN, 256, 0, stream>>>(cnt_p, rs, bsum);
  k_scanB<<<1, 256, 0, stream>>>(bsum, boff);
  k_scanC<<<gN, B, 0, stream>>>(rs, boff, fill_p);
  k_scatter<<<gE, B, 0, stream>>>(ei, ew, ea, fill_p, edges);
  k_deg<<<gN, B, 0, stream>>>(edges, rs, dinv, scal);
  k_norm<<<gE, B, 0, stream>>>(edges, dinv);

  const float* xin = x;
  for (int l = 0; l < 2; ++l) {
    float* xout = (l == 0) ? xmid : (float*)d_out;
    k_dual_gemm<<<gRB, B, 0, stream>>>(xin, P[l][0], P[l][2], P[l][3], hb, resb, NN);
    k_gcn_agg<<<gNW, B, 0, stream>>>(hb, resb, dinv, rs, edges,
                                     P[l][1], P[l][4], P[l][5], x2b, NN);
    k_gat_node<<<gRB, B, 0, stream>>>(x2b, P[l][6], P[l][8], P[l][9], xlb, asb, adb, NN);
    k_gat_agg<<<gNW, B, 0, stream>>>(xlb, x2b, asb, adb, rs, edges,
                                     P[l][11], P[l][10], scal, P[l][7], xout, NN);
    xin = xout;
  }
}

// Round 4
// 493.646 us; speedup vs baseline: 2.1242x; 1.1866x over previous
//
#include <hip/hip_runtime.h>

#define NN 50000
#define NE 800000
#define D 64
#define EPS 1e-5f
#define PAD 16  // ints per counter slot -> one 64B line each
#define RB 8    // rows per wave in GEMM kernels (8 | 50000)

typedef unsigned short ushort_t;

__device__ __forceinline__ float wave_sum64(float v) {
#pragma unroll
  for (int m = 1; m <= 32; m <<= 1) v += __shfl_xor(v, m, 64);
  return v;
}
__device__ __forceinline__ float group_sum16(float v) {
#pragma unroll
  for (int m = 1; m <= 8; m <<= 1) v += __shfl_xor(v, m, 64);
  return v;
}
__device__ __forceinline__ float silu_f(float v) { return v / (1.f + __expf(-v)); }
__device__ __forceinline__ float lrelu_f(float v) { return v >= 0.f ? v : 0.2f * v; }
// bf16 pack (RNE) / unpack
__device__ __forceinline__ ushort_t f2b(float x) {
  unsigned u = __float_as_uint(x);
  return (ushort_t)((u + 0x7FFFu + ((u >> 16) & 1u)) >> 16);
}
__device__ __forceinline__ float b2f(ushort_t u) {
  return __uint_as_float(((unsigned)u) << 16);
}
__device__ __forceinline__ float sel4(float a, float b, float c, float d, int h) {
  float ab = (h & 1) ? b : a;
  float cd = (h & 1) ? d : c;
  return (h & 2) ? cd : ab;
}

// ---------- graph preprocessing ----------

__global__ void k_hist(const int* __restrict__ ei, const float* __restrict__ ea,
                       int* __restrict__ cnt_p, float* __restrict__ scal) {
  int e = blockIdx.x * blockDim.x + threadIdx.x;
  float a = 0.f;
  if (e < NE) {
    int dst = ei[NE + e];
    atomicAdd(&cnt_p[(size_t)dst * PAD], 1);
    a = ea[e];
  }
  a = wave_sum64(a);
  if ((threadIdx.x & 63) == 0) {
    int slot = (blockIdx.x * 4 + (threadIdx.x >> 6)) & 63;
    atomicAdd(&scal[(size_t)slot * 16], a);
  }
}

__global__ void k_scanA(const int* __restrict__ cnt_p, int* __restrict__ rs,
                        int* __restrict__ bsum) {
  __shared__ int sm[256];
  int j = threadIdx.x, i = blockIdx.x * 256 + j;
  int v = (i < NN) ? cnt_p[(size_t)i * PAD] : 0;
  sm[j] = v;
  __syncthreads();
  for (int off = 1; off < 256; off <<= 1) {
    int t = (j >= off) ? sm[j - off] : 0;
    __syncthreads();
    sm[j] += t;
    __syncthreads();
  }
  if (i < NN) rs[i] = sm[j] - v;
  if (j == 255) bsum[blockIdx.x] = sm[255];
}

__global__ void k_scanB(const int* __restrict__ bsum, int* __restrict__ boff) {
  __shared__ int sm[256];
  int j = threadIdx.x;
  const int nb = (NN + 255) / 256;
  int v = (j < nb) ? bsum[j] : 0;
  sm[j] = v;
  __syncthreads();
  for (int off = 1; off < 256; off <<= 1) {
    int t = (j >= off) ? sm[j - off] : 0;
    __syncthreads();
    sm[j] += t;
    __syncthreads();
  }
  if (j < nb) boff[j] = sm[j] - v;
}

__global__ void k_scanC(int* __restrict__ rs, const int* __restrict__ boff,
                        int* __restrict__ fill_p) {
  int i = blockIdx.x * blockDim.x + threadIdx.x;
  if (i < NN) {
    int r = rs[i] + boff[i >> 8];
    rs[i] = r;
    fill_p[(size_t)i * PAD] = r;
  }
  if (i == 0) rs[NN] = NE;
}

__global__ void k_scatter(const int* __restrict__ ei, const float* __restrict__ ew,
                          const float* __restrict__ ea, int* __restrict__ fill_p,
                          float4* __restrict__ edges) {
  int e = blockIdx.x * blockDim.x + threadIdx.x;
  if (e >= NE) return;
  int src = ei[e];
  int dst = ei[NE + e];
  int slot = atomicAdd(&fill_p[(size_t)dst * PAD], 1);
  float4 f;
  f.x = __int_as_float(src);
  f.y = ew[e];
  f.z = ea[e];
  f.w = __int_as_float(dst);
  edges[slot] = f;
}

__global__ void k_deg(const float4* __restrict__ edges, const int* __restrict__ rs,
                      float* __restrict__ dinv, float* __restrict__ scal) {
  int i = blockIdx.x * blockDim.x + threadIdx.x;
  if (i < NN) {
    float s = 1.f;
    int k1 = rs[i + 1];
    for (int k = rs[i]; k < k1; ++k) s += edges[k].y;
    dinv[i] = rsqrtf(s);
  }
  if (i == 0) {
    float t = 0.f;
    for (int j = 0; j < 64; ++j) t += scal[(size_t)j * 16];
    scal[1] = t / (float)NE;
  }
}

__global__ void k_norm(float4* __restrict__ edges, const float* __restrict__ dinv) {
  int e = blockIdx.x * blockDim.x + threadIdx.x;
  if (e >= NE) return;
  float4 f = edges[e];
  int src = __float_as_int(f.x), dst = __float_as_int(f.w);
  f.y *= dinv[src] * dinv[dst];
  edges[e] = f;
}

// ---------- dense ops (8 rows per wave) ----------

// out1 = bf16(x @ W1) ; out2 = x @ W2 + b2
__global__ void __launch_bounds__(256) k_dual_gemm(
    const float* __restrict__ x, const float* __restrict__ W1,
    const float* __restrict__ W2, const float* __restrict__ b2,
    ushort_t* __restrict__ out1, float* __restrict__ out2, int n) {
  int wv = (blockIdx.x * blockDim.x + threadIdx.x) >> 6;
  int c = threadIdx.x & 63;
  int r0 = wv * RB;
  if (r0 >= n) return;
  const float* xr = x + (size_t)r0 * D;
  float a1[RB] = {0.f, 0.f, 0.f, 0.f, 0.f, 0.f, 0.f, 0.f};
  float a2[RB] = {0.f, 0.f, 0.f, 0.f, 0.f, 0.f, 0.f, 0.f};
#pragma unroll 2
  for (int k = 0; k < D; k += 4) {
    float w10 = W1[(k + 0) * D + c], w11 = W1[(k + 1) * D + c];
    float w12 = W1[(k + 2) * D + c], w13 = W1[(k + 3) * D + c];
    float w20 = W2[(k + 0) * D + c], w21 = W2[(k + 1) * D + c];
    float w22 = W2[(k + 2) * D + c], w23 = W2[(k + 3) * D + c];
#pragma unroll
    for (int r = 0; r < RB; ++r) {
      float4 xv = *(const float4*)(xr + (size_t)r * D + k);
      a1[r] = fmaf(xv.x, w10, a1[r]); a2[r] = fmaf(xv.x, w20, a2[r]);
      a1[r] = fmaf(xv.y, w11, a1[r]); a2[r] = fmaf(xv.y, w21, a2[r]);
      a1[r] = fmaf(xv.z, w12, a1[r]); a2[r] = fmaf(xv.z, w22, a2[r]);
      a1[r] = fmaf(xv.w, w13, a1[r]); a2[r] = fmaf(xv.w, w23, a2[r]);
    }
  }
  float bb = b2[c];
#pragma unroll
  for (int r = 0; r < RB; ++r) {
    out1[(size_t)(r0 + r) * D + c] = f2b(a1[r]);
    out2[(size_t)(r0 + r) * D + c] = a2[r] + bb;
  }
}

// xl16 = bf16(x2 @ Wg) ; per-head a_s, a_d (from fp32 accs). Block 0 wave 0
// also computes weA[h] = sum_c We[c]*a_e[c] per head into wea[4].
__global__ void __launch_bounds__(256) k_gat_node(
    const float* __restrict__ x2, const float* __restrict__ Wg,
    const float* __restrict__ att_src, const float* __restrict__ att_dst,
    const float* __restrict__ We, const float* __restrict__ a_e,
    ushort_t* __restrict__ xl, float* __restrict__ a_s, float* __restrict__ a_d,
    float* __restrict__ wea, int n) {
  if (blockIdx.x == 0 && threadIdx.x < 64) {
    int c = threadIdx.x;
    float v = group_sum16(We[c] * a_e[c]);
    if ((c & 15) == 0) wea[c >> 4] = v;
  }
  int wv = (blockIdx.x * blockDim.x + threadIdx.x) >> 6;
  int c = threadIdx.x & 63;
  int r0 = wv * RB;
  if (r0 >= n) return;
  const float* xr = x2 + (size_t)r0 * D;
  float acc[RB] = {0.f, 0.f, 0.f, 0.f, 0.f, 0.f, 0.f, 0.f};
#pragma unroll 2
  for (int k = 0; k < D; k += 4) {
    float w0 = Wg[(k + 0) * D + c], w1 = Wg[(k + 1) * D + c];
    float w2 = Wg[(k + 2) * D + c], w3 = Wg[(k + 3) * D + c];
#pragma unroll
    for (int r = 0; r < RB; ++r) {
      float4 xv = *(const float4*)(xr + (size_t)r * D + k);
      acc[r] = fmaf(xv.x, w0, acc[r]);
      acc[r] = fmaf(xv.y, w1, acc[r]);
      acc[r] = fmaf(xv.z, w2, acc[r]);
      acc[r] = fmaf(xv.w, w3, acc[r]);
    }
  }
  float asv = att_src[c], adv = att_dst[c];
#pragma unroll
  for (int r = 0; r < RB; ++r) {
    xl[(size_t)(r0 + r) * D + c] = f2b(acc[r]);
    float vs = group_sum16(acc[r] * asv);
    float vd = group_sum16(acc[r] * adv);
    if ((c & 15) == 0) {
      a_s[(size_t)(r0 + r) * 4 + (c >> 4)] = vs;
      a_d[(size_t)(r0 + r) * 4 + (c >> 4)] = vd;
    }
  }
}

// GCN aggregate + bias + silu + residual + LayerNorm. One wave per node.
// Edge chunks staged cooperatively through LDS (coalesced loads, broadcast reads).
__global__ void __launch_bounds__(256) k_gcn_agg(
    const ushort_t* __restrict__ h16, const float* __restrict__ res,
    const float* __restrict__ dinv, const int* __restrict__ rs,
    const float4* __restrict__ edges,
    const float* __restrict__ gb, const float* __restrict__ lg, const float* __restrict__ lb,
    float* __restrict__ x2, int n) {
  __shared__ int   ss[4][64];
  __shared__ float swt[4][64];
  int w = threadIdx.x >> 6;
  int i = (blockIdx.x * blockDim.x + threadIdx.x) >> 6;
  int c = threadIdx.x & 63;
  if (i >= n) return;
  float di = dinv[i];
  float acc = di * di * b2f(h16[(size_t)i * D + c]);
  int k0 = rs[i], k1 = rs[i + 1];
  for (int base = k0; base < k1; base += 64) {
    int cnt = min(64, k1 - base);
    int src = i; float ww = 0.f;
    if (c < cnt) {
      float4 e = edges[base + c];
      src = __float_as_int(e.x);
      ww = e.y;
    }
    ss[w][c] = src;
    swt[w][c] = ww;
    int cnt4 = (cnt + 3) & ~3;
    for (int j = 0; j < cnt4; j += 4) {
      int4 s4 = *(const int4*)&ss[w][j];
      float4 w4 = *(const float4*)&swt[w][j];
      float x0 = b2f(h16[(size_t)s4.x * D + c]);
      float x1 = b2f(h16[(size_t)s4.y * D + c]);
      float x2v = b2f(h16[(size_t)s4.z * D + c]);
      float x3v = b2f(h16[(size_t)s4.w * D + c]);
      acc = fmaf(w4.x, x0, acc);
      acc = fmaf(w4.y, x1, acc);
      acc = fmaf(w4.z, x2v, acc);
      acc = fmaf(w4.w, x3v, acc);
    }
  }
  float v = acc + gb[c];
  float x1 = silu_f(v) + res[(size_t)i * D + c];
  float mu = wave_sum64(x1) * (1.f / 64.f);
  float d = x1 - mu;
  float var = wave_sum64(d * d) * (1.f / 64.f);
  x2[(size_t)i * D + c] = d * rsqrtf(var + EPS) * lg[c] + lb[c];
}

// GAT aggregate (no-max softmax: alphas are O(+-10), exp safe in fp32; softmax
// is shift-invariant and ref's s >= exp(al_max-m)=1 keeps +1e-16 negligible).
// Per chunk: lane l computes edge l's 4 head exps ONCE (vs 16x redundant),
// stages (src, e[4]) in LDS; gather loop reads via broadcast ds_read_b128.
__global__ void __launch_bounds__(256) k_gat_agg(
    const ushort_t* __restrict__ xl16, const float* __restrict__ x2,
    const float* __restrict__ a_s, const float* __restrict__ a_d,
    const int* __restrict__ rs, const float4* __restrict__ edges,
    const float* __restrict__ wea, const float* __restrict__ scal,
    const float* __restrict__ bg, float* __restrict__ xout, int n) {
  __shared__ int   ss[4][64];
  __shared__ float el[4][4][68];  // [wave][head][slot], pad 68 to split banks per head
  int w = threadIdx.x >> 6;
  int i = (blockIdx.x * blockDim.x + threadIdx.x) >> 6;
  int l = threadIdx.x & 63;
  if (i >= n) return;
  int hh = l >> 4;
  float4 ad4 = *(const float4*)(a_d + (size_t)i * 4);
  float4 wv4 = *(const float4*)wea;
  float mean_attr = scal[1];
  float ad_h = sel4(ad4.x, ad4.y, ad4.z, ad4.w, hh);
  float we_h = sel4(wv4.x, wv4.y, wv4.z, wv4.w, hh);
  float as_i = a_s[(size_t)i * 4 + hh];
  float e_self = __expf(lrelu_f(as_i + ad_h + mean_attr * we_h));
  float s_acc = e_self;
  float acc = e_self * b2f(xl16[(size_t)i * D + l]);
  int k0 = rs[i], k1 = rs[i + 1];
  for (int base = k0; base < k1; base += 64) {
    int cnt = min(64, k1 - base);
    int src = i;
    float e0v = 0.f, e1v = 0.f, e2v = 0.f, e3v = 0.f;
    if (l < cnt) {
      float4 e = edges[base + l];
      src = __float_as_int(e.x);
      float4 as4 = *(const float4*)(a_s + (size_t)src * 4);
      float ea = e.z;
      e0v = __expf(lrelu_f(as4.x + fmaf(ea, wv4.x, ad4.x)));
      e1v = __expf(lrelu_f(as4.y + fmaf(ea, wv4.y, ad4.y)));
      e2v = __expf(lrelu_f(as4.z + fmaf(ea, wv4.z, ad4.z)));
      e3v = __expf(lrelu_f(as4.w + fmaf(ea, wv4.w, ad4.w)));
    }
    ss[w][l] = src;
    el[w][0][l] = e0v;
    el[w][1][l] = e1v;
    el[w][2][l] = e2v;
    el[w][3][l] = e3v;
    int cnt4 = (cnt + 3) & ~3;
    for (int j = 0; j < cnt4; j += 4) {
      int4 s4 = *(const int4*)&ss[w][j];
      float4 e4 = *(const float4*)&el[w][hh][j];
      float x0 = b2f(xl16[(size_t)s4.x * D + l]);
      float x1 = b2f(xl16[(size_t)s4.y * D + l]);
      float x2v = b2f(xl16[(size_t)s4.z * D + l]);
      float x3v = b2f(xl16[(size_t)s4.w * D + l]);
      acc = fmaf(e4.x, x0, acc);
      acc = fmaf(e4.y, x1, acc);
      acc = fmaf(e4.z, x2v, acc);
      acc = fmaf(e4.w, x3v, acc);
      s_acc += (e4.x + e4.y) + (e4.z + e4.w);
    }
  }
  float o = acc / (s_acc + 1e-16f) + bg[l];
  xout[(size_t)i * D + l] = silu_f(o) + x2[(size_t)i * D + l];
}

// ---------- launch ----------

extern "C" void kernel_launch(void* const* d_in, const int* in_sizes, int n_in,
                              void* d_out, int out_size, void* d_ws, size_t ws_size,
                              hipStream_t stream) {
  (void)in_sizes; (void)n_in; (void)out_size; (void)ws_size;
  const float* x  = (const float*)d_in[0];
  const int*   ei = (const int*)d_in[1];
  const float* ew = (const float*)d_in[2];
  const float* ea = (const float*)d_in[3];
  const float* P[2][12];
  for (int l = 0; l < 2; ++l)
    for (int j = 0; j < 12; ++j) P[l][j] = (const float*)d_in[4 + l * 12 + j];

  float* W = (float*)d_ws;
  // layout (float units); o_edges must stay 16B-aligned
  const size_t o_rs    = 0;                        // NN+16
  const size_t o_dinv  = o_rs + NN + 16;           // NN
  const size_t o_scal  = o_dinv + NN;              // 1024
  const size_t o_bsum  = o_scal + 1024;            // 256
  const size_t o_boff  = o_bsum + 256;             // 256
  const size_t o_wea   = o_boff + 256;             // 16
  const size_t o_edges = o_wea + 16;               // NE*4
  const size_t o_h16   = o_edges + (size_t)NE * 4; // NN*D/2 (ushort NN*D)
  const size_t o_xl16  = o_h16 + (size_t)NN * D / 2;
  const size_t o_res   = o_xl16 + (size_t)NN * D / 2;
  const size_t o_x2    = o_res + (size_t)NN * D;
  const size_t o_xmid  = o_x2 + (size_t)NN * D;
  const size_t o_as    = o_xmid + (size_t)NN * D;  // NN*4
  const size_t o_ad    = o_as + (size_t)NN * 4;    // NN*4

  int*      rs    = (int*)(W + o_rs);
  float*    dinv  = W + o_dinv;
  float*    scal  = W + o_scal;
  int*      bsum  = (int*)(W + o_bsum);
  int*      boff  = (int*)(W + o_boff);
  float*    wea   = W + o_wea;
  float4*   edges = (float4*)(W + o_edges);
  ushort_t* h16   = (ushort_t*)(W + o_h16);
  ushort_t* xl16  = (ushort_t*)(W + o_xl16);
  float*    resb  = W + o_res;
  float*    x2b   = W + o_x2;
  float*    xmid  = W + o_xmid;
  float*    asb   = W + o_as;
  float*    adb   = W + o_ad;
  int*      cnt_p  = (int*)x2b;   // prep-phase alias (dead during prep)
  int*      fill_p = (int*)xmid;  // prep-phase alias

  const int B = 256;
  const int gN  = (NN + B - 1) / B;
  const int gE  = (NE + B - 1) / B;
  const int gNW = (NN * D + B - 1) / B;                  // wave per node
  const int gRB = ((NN + RB - 1) / RB * 64 + B - 1) / B; // wave per RB rows

  hipMemsetAsync(cnt_p, 0, (size_t)NN * PAD * sizeof(int), stream);
  hipMemsetAsync(scal, 0, 1024 * sizeof(float), stream);
  k_hist<<<gE, B, 0, stream>>>(ei, ea, cnt_p, scal);
  k_scanA<<<gN, 256, 0, stream>>>(cnt_p, rs, bsum);
  k_scanB<<<1, 256, 0, stream>>>(bsum, boff);
  k_scanC<<<gN, B, 0, stream>>>(rs, boff, fill_p);
  k_scatter<<<gE, B, 0, stream>>>(ei, ew, ea, fill_p, edges);
  k_deg<<<gN, B, 0, stream>>>(edges, rs, dinv, scal);
  k_norm<<<gE, B, 0, stream>>>(edges, dinv);

  const float* xin = x;
  for (int l = 0; l < 2; ++l) {
    float* xout = (l == 0) ? xmid : (float*)d_out;
    k_dual_gemm<<<gRB, B, 0, stream>>>(xin, P[l][0], P[l][2], P[l][3], h16, resb, NN);
    k_gcn_agg<<<gNW, B, 0, stream>>>(h16, resb, dinv, rs, edges,
                                     P[l][1], P[l][4], P[l][5], x2b, NN);
    k_gat_node<<<gRB, B, 0, stream>>>(x2b, P[l][6], P[l][8], P[l][9],
                                      P[l][11], P[l][10], xl16, asb, adb, wea, NN);
    k_gat_agg<<<gNW, B, 0, stream>>>(xl16, x2b, asb, adb, rs, edges,
                                     wea, scal, P[l][7], xout, NN);
    xin = xout;
  }
}

// Round 5
// 452.301 us; speedup vs baseline: 2.3184x; 1.0914x over previous
//
#include <hip/hip_runtime.h>
#include <hip/hip_fp16.h>

#define NN 50000
#define NE 800000
#define D 64
#define EPS 1e-5f
#define PAD 16  // ints per counter slot -> one 64B line each
#define RB 8    // rows per wave in GEMM kernels (8 | 50000)

typedef unsigned short ushort_t;
typedef unsigned int uint_t;

__device__ __forceinline__ float wave_sum64(float v) {
#pragma unroll
  for (int m = 1; m <= 32; m <<= 1) v += __shfl_xor(v, m, 64);
  return v;
}
__device__ __forceinline__ float group_sum16(float v) {
#pragma unroll
  for (int m = 1; m <= 8; m <<= 1) v += __shfl_xor(v, m, 64);
  return v;
}
__device__ __forceinline__ float silu_f(float v) { return v / (1.f + __expf(-v)); }
__device__ __forceinline__ float lrelu_f(float v) { return v >= 0.f ? v : 0.2f * v; }
// bf16 pack (RNE) / unpack
__device__ __forceinline__ ushort_t f2b(float x) {
  unsigned u = __float_as_uint(x);
  return (ushort_t)((u + 0x7FFFu + ((u >> 16) & 1u)) >> 16);
}
__device__ __forceinline__ float b2f(ushort_t u) {
  return __uint_as_float(((unsigned)u) << 16);
}
// fp16 pack/unpack (for edge payloads)
__device__ __forceinline__ ushort_t f2h(float x) {
  return __half_as_ushort(__float2half_rn(x));
}
__device__ __forceinline__ float h2f(unsigned u) {
  return __half2float(__ushort_as_half((ushort_t)(u & 0xFFFFu)));
}
__device__ __forceinline__ float sel4(float a, float b, float c, float d, int h) {
  float ab = (h & 1) ? b : a;
  float cd = (h & 1) ? d : c;
  return (h & 2) ? cd : ab;
}

// ---------- graph preprocessing ----------
// ONE device-atomic pass: rank[e] = arrival index within dst's segment.
__global__ void k_histrank(const int* __restrict__ ei, int* __restrict__ cnt_p,
                           int* __restrict__ rank) {
  int e = blockIdx.x * blockDim.x + threadIdx.x;
  if (e >= NE) return;
  int dst = ei[NE + e];
  rank[e] = atomicAdd(&cnt_p[(size_t)dst * PAD], 1);
}

__global__ void k_scanA(const int* __restrict__ cnt_p, int* __restrict__ rs,
                        int* __restrict__ bsum) {
  __shared__ int sm[256];
  int j = threadIdx.x, i = blockIdx.x * 256 + j;
  int v = (i < NN) ? cnt_p[(size_t)i * PAD] : 0;
  sm[j] = v;
  __syncthreads();
  for (int off = 1; off < 256; off <<= 1) {
    int t = (j >= off) ? sm[j - off] : 0;
    __syncthreads();
    sm[j] += t;
    __syncthreads();
  }
  if (i < NN) rs[i] = sm[j] - v;
  if (j == 255) bsum[blockIdx.x] = sm[255];
}

__global__ void k_scanB(const int* __restrict__ bsum, int* __restrict__ boff) {
  __shared__ int sm[256];
  int j = threadIdx.x;
  const int nb = (NN + 255) / 256;
  int v = (j < nb) ? bsum[j] : 0;
  sm[j] = v;
  __syncthreads();
  for (int off = 1; off < 256; off <<= 1) {
    int t = (j >= off) ? sm[j - off] : 0;
    __syncthreads();
    sm[j] += t;
    __syncthreads();
  }
  if (j < nb) boff[j] = sm[j] - v;
}

__global__ void k_scanC(int* __restrict__ rs, const int* __restrict__ boff) {
  int i = blockIdx.x * blockDim.x + threadIdx.x;
  if (i < NN) rs[i] = rs[i] + boff[i >> 8];
  if (i == 0) rs[NN] = NE;
}

// No atomics: slot = rs[dst] + rank[e]. Writes split 4B records:
//   grec[slot] = src | f16(ew)<<16   (GCN + deg)
//   arec[slot] = src | f16(ea)<<16   (GAT)
// Also accumulates edge_attr partial sums for the mean (64 padded slots).
__global__ void k_place(const int* __restrict__ ei, const float* __restrict__ ew,
                        const float* __restrict__ ea, const int* __restrict__ rank,
                        const int* __restrict__ rs,
                        uint_t* __restrict__ grec, uint_t* __restrict__ arec,
                        float* __restrict__ scal) {
  int e = blockIdx.x * blockDim.x + threadIdx.x;
  float a = 0.f;
  if (e < NE) {
    int src = ei[e];
    int dst = ei[NE + e];
    float w = ew[e];
    a = ea[e];
    int slot = rs[dst] + rank[e];
    grec[slot] = (uint_t)(src & 0xFFFF) | ((uint_t)f2h(w) << 16);
    arec[slot] = (uint_t)(src & 0xFFFF) | ((uint_t)f2h(a) << 16);
  }
  float s = wave_sum64(a);
  if ((threadIdx.x & 63) == 0) {
    int slot = (blockIdx.x * 4 + (threadIdx.x >> 6)) & 63;
    atomicAdd(&scal[(size_t)slot * 16], s);
  }
}

// deg from CSR (contiguous reads); thread 0 finalizes mean edge_attr
__global__ void k_deg(const uint_t* __restrict__ grec, const int* __restrict__ rs,
                      float* __restrict__ dinv, float* __restrict__ scal) {
  int i = blockIdx.x * blockDim.x + threadIdx.x;
  if (i < NN) {
    float s = 1.f;  // self loop weight
    int k1 = rs[i + 1];
    for (int k = rs[i]; k < k1; ++k) s += h2f(grec[k] >> 16);
    dinv[i] = rsqrtf(s);
  }
  if (i == 0) {
    float t = 0.f;
    for (int j = 0; j < 64; ++j) t += scal[(size_t)j * 16];
    scal[1] = t / (float)NE;
  }
}

// ---------- dense ops (8 rows per wave) ----------

__global__ void __launch_bounds__(256) k_dual_gemm(
    const float* __restrict__ x, const float* __restrict__ W1,
    const float* __restrict__ W2, const float* __restrict__ b2,
    ushort_t* __restrict__ out1, float* __restrict__ out2, int n) {
  int wv = (blockIdx.x * blockDim.x + threadIdx.x) >> 6;
  int c = threadIdx.x & 63;
  int r0 = wv * RB;
  if (r0 >= n) return;
  const float* xr = x + (size_t)r0 * D;
  float a1[RB] = {0.f, 0.f, 0.f, 0.f, 0.f, 0.f, 0.f, 0.f};
  float a2[RB] = {0.f, 0.f, 0.f, 0.f, 0.f, 0.f, 0.f, 0.f};
#pragma unroll 2
  for (int k = 0; k < D; k += 4) {
    float w10 = W1[(k + 0) * D + c], w11 = W1[(k + 1) * D + c];
    float w12 = W1[(k + 2) * D + c], w13 = W1[(k + 3) * D + c];
    float w20 = W2[(k + 0) * D + c], w21 = W2[(k + 1) * D + c];
    float w22 = W2[(k + 2) * D + c], w23 = W2[(k + 3) * D + c];
#pragma unroll
    for (int r = 0; r < RB; ++r) {
      float4 xv = *(const float4*)(xr + (size_t)r * D + k);
      a1[r] = fmaf(xv.x, w10, a1[r]); a2[r] = fmaf(xv.x, w20, a2[r]);
      a1[r] = fmaf(xv.y, w11, a1[r]); a2[r] = fmaf(xv.y, w21, a2[r]);
      a1[r] = fmaf(xv.z, w12, a1[r]); a2[r] = fmaf(xv.z, w22, a2[r]);
      a1[r] = fmaf(xv.w, w13, a1[r]); a2[r] = fmaf(xv.w, w23, a2[r]);
    }
  }
  float bb = b2[c];
#pragma unroll
  for (int r = 0; r < RB; ++r) {
    out1[(size_t)(r0 + r) * D + c] = f2b(a1[r]);
    out2[(size_t)(r0 + r) * D + c] = a2[r] + bb;
  }
}

__global__ void __launch_bounds__(256) k_gat_node(
    const float* __restrict__ x2, const float* __restrict__ Wg,
    const float* __restrict__ att_src, const float* __restrict__ att_dst,
    const float* __restrict__ We, const float* __restrict__ a_e,
    ushort_t* __restrict__ xl, float* __restrict__ a_s, float* __restrict__ a_d,
    float* __restrict__ wea, int n) {
  if (blockIdx.x == 0 && threadIdx.x < 64) {
    int c = threadIdx.x;
    float v = group_sum16(We[c] * a_e[c]);
    if ((c & 15) == 0) wea[c >> 4] = v;
  }
  int wv = (blockIdx.x * blockDim.x + threadIdx.x) >> 6;
  int c = threadIdx.x & 63;
  int r0 = wv * RB;
  if (r0 >= n) return;
  const float* xr = x2 + (size_t)r0 * D;
  float acc[RB] = {0.f, 0.f, 0.f, 0.f, 0.f, 0.f, 0.f, 0.f};
#pragma unroll 2
  for (int k = 0; k < D; k += 4) {
    float w0 = Wg[(k + 0) * D + c], w1 = Wg[(k + 1) * D + c];
    float w2 = Wg[(k + 2) * D + c], w3 = Wg[(k + 3) * D + c];
#pragma unroll
    for (int r = 0; r < RB; ++r) {
      float4 xv = *(const float4*)(xr + (size_t)r * D + k);
      acc[r] = fmaf(xv.x, w0, acc[r]);
      acc[r] = fmaf(xv.y, w1, acc[r]);
      acc[r] = fmaf(xv.z, w2, acc[r]);
      acc[r] = fmaf(xv.w, w3, acc[r]);
    }
  }
  float asv = att_src[c], adv = att_dst[c];
#pragma unroll
  for (int r = 0; r < RB; ++r) {
    xl[(size_t)(r0 + r) * D + c] = f2b(acc[r]);
    float vs = group_sum16(acc[r] * asv);
    float vd = group_sum16(acc[r] * adv);
    if ((c & 15) == 0) {
      a_s[(size_t)(r0 + r) * 4 + (c >> 4)] = vs;
      a_d[(size_t)(r0 + r) * 4 + (c >> 4)] = vd;
    }
  }
}

// GCN aggregate + bias + silu + residual + LayerNorm. One wave per node.
// Stage lane normalizes: wn = dinv[src] * f16w * dinv[i].
__global__ void __launch_bounds__(256) k_gcn_agg(
    const ushort_t* __restrict__ h16, const float* __restrict__ res,
    const float* __restrict__ dinv, const int* __restrict__ rs,
    const uint_t* __restrict__ grec,
    const float* __restrict__ gb, const float* __restrict__ lg, const float* __restrict__ lb,
    float* __restrict__ x2, int n) {
  __shared__ int   ss[4][64];
  __shared__ float swt[4][64];
  int w = threadIdx.x >> 6;
  int i = (blockIdx.x * blockDim.x + threadIdx.x) >> 6;
  int c = threadIdx.x & 63;
  if (i >= n) return;
  float di = dinv[i];
  float acc = di * di * b2f(h16[(size_t)i * D + c]);
  int k0 = rs[i], k1 = rs[i + 1];
  for (int base = k0; base < k1; base += 64) {
    int cnt = min(64, k1 - base);
    int src = 0; float wn = 0.f;
    if (c < cnt) {
      uint_t r = grec[base + c];
      src = (int)(r & 0xFFFFu);
      wn = dinv[src] * h2f(r >> 16) * di;
    }
    ss[w][c] = src;
    swt[w][c] = wn;
    int cnt4 = (cnt + 3) & ~3;
    for (int j = 0; j < cnt4; j += 4) {
      int4 s4 = *(const int4*)&ss[w][j];
      float4 w4 = *(const float4*)&swt[w][j];
      float x0 = b2f(h16[(size_t)s4.x * D + c]);
      float x1 = b2f(h16[(size_t)s4.y * D + c]);
      float x2v = b2f(h16[(size_t)s4.z * D + c]);
      float x3v = b2f(h16[(size_t)s4.w * D + c]);
      acc = fmaf(w4.x, x0, acc);
      acc = fmaf(w4.y, x1, acc);
      acc = fmaf(w4.z, x2v, acc);
      acc = fmaf(w4.w, x3v, acc);
    }
  }
  float v = acc + gb[c];
  float x1 = silu_f(v) + res[(size_t)i * D + c];
  float mu = wave_sum64(x1) * (1.f / 64.f);
  float d = x1 - mu;
  float var = wave_sum64(d * d) * (1.f / 64.f);
  x2[(size_t)i * D + c] = d * rsqrtf(var + EPS) * lg[c] + lb[c];
}

// GAT aggregate, no-max softmax (alphas O(+-10), shift-invariant), per-edge
// exps computed once by the stage lane, broadcast via LDS.
__global__ void __launch_bounds__(256) k_gat_agg(
    const ushort_t* __restrict__ xl16, const float* __restrict__ x2,
    const float* __restrict__ a_s, const float* __restrict__ a_d,
    const int* __restrict__ rs, const uint_t* __restrict__ arec,
    const float* __restrict__ wea, const float* __restrict__ scal,
    const float* __restrict__ bg, float* __restrict__ xout, int n) {
  __shared__ int   ss[4][64];
  __shared__ float el[4][4][68];
  int w = threadIdx.x >> 6;
  int i = (blockIdx.x * blockDim.x + threadIdx.x) >> 6;
  int l = threadIdx.x & 63;
  if (i >= n) return;
  int hh = l >> 4;
  float4 ad4 = *(const float4*)(a_d + (size_t)i * 4);
  float4 wv4 = *(const float4*)wea;
  float mean_attr = scal[1];
  float ad_h = sel4(ad4.x, ad4.y, ad4.z, ad4.w, hh);
  float we_h = sel4(wv4.x, wv4.y, wv4.z, wv4.w, hh);
  float as_i = a_s[(size_t)i * 4 + hh];
  float e_self = __expf(lrelu_f(as_i + ad_h + mean_attr * we_h));
  float s_acc = e_self;
  float acc = e_self * b2f(xl16[(size_t)i * D + l]);
  int k0 = rs[i], k1 = rs[i + 1];
  for (int base = k0; base < k1; base += 64) {
    int cnt = min(64, k1 - base);
    int src = 0;
    float e0v = 0.f, e1v = 0.f, e2v = 0.f, e3v = 0.f;
    if (l < cnt) {
      uint_t r = arec[base + l];
      src = (int)(r & 0xFFFFu);
      float ea = h2f(r >> 16);
      float4 as4 = *(const float4*)(a_s + (size_t)src * 4);
      e0v = __expf(lrelu_f(as4.x + fmaf(ea, wv4.x, ad4.x)));
      e1v = __expf(lrelu_f(as4.y + fmaf(ea, wv4.y, ad4.y)));
      e2v = __expf(lrelu_f(as4.z + fmaf(ea, wv4.z, ad4.z)));
      e3v = __expf(lrelu_f(as4.w + fmaf(ea, wv4.w, ad4.w)));
    }
    ss[w][l] = src;
    el[w][0][l] = e0v;
    el[w][1][l] = e1v;
    el[w][2][l] = e2v;
    el[w][3][l] = e3v;
    int cnt4 = (cnt + 3) & ~3;
    for (int j = 0; j < cnt4; j += 4) {
      int4 s4 = *(const int4*)&ss[w][j];
      float4 e4 = *(const float4*)&el[w][hh][j];
      float x0 = b2f(xl16[(size_t)s4.x * D + l]);
      float x1 = b2f(xl16[(size_t)s4.y * D + l]);
      float x2v = b2f(xl16[(size_t)s4.z * D + l]);
      float x3v = b2f(xl16[(size_t)s4.w * D + l]);
      acc = fmaf(e4.x, x0, acc);
      acc = fmaf(e4.y, x1, acc);
      acc = fmaf(e4.z, x2v, acc);
      acc = fmaf(e4.w, x3v, acc);
      s_acc += (e4.x + e4.y) + (e4.z + e4.w);
    }
  }
  float o = acc / (s_acc + 1e-16f) + bg[l];
  xout[(size_t)i * D + l] = silu_f(o) + x2[(size_t)i * D + l];
}

// ---------- launch ----------

extern "C" void kernel_launch(void* const* d_in, const int* in_sizes, int n_in,
                              void* d_out, int out_size, void* d_ws, size_t ws_size,
                              hipStream_t stream) {
  (void)in_sizes; (void)n_in; (void)out_size; (void)ws_size;
  const float* x  = (const float*)d_in[0];
  const int*   ei = (const int*)d_in[1];
  const float* ew = (const float*)d_in[2];
  const float* ea = (const float*)d_in[3];
  const float* P[2][12];
  for (int l = 0; l < 2; ++l)
    for (int j = 0; j < 12; ++j) P[l][j] = (const float*)d_in[4 + l * 12 + j];

  float* W = (float*)d_ws;
  // layout in float units (all offsets multiples of 16 for float4 alignment)
  const size_t o_rs    = 0;                         // NN+16 ints
  const size_t o_dinv  = o_rs + NN + 16;            // NN
  const size_t o_scal  = o_dinv + NN;               // 1024
  const size_t o_bsum  = o_scal + 1024;             // 256
  const size_t o_boff  = o_bsum + 256;              // 256
  const size_t o_wea   = o_boff + 256;              // 16
  const size_t o_grec  = o_wea + 16;                // NE uints
  const size_t o_arec  = o_grec + NE;               // NE uints
  const size_t o_h16   = o_arec + NE;               // NN*D ushort = NN*D/2 floats
  const size_t o_xl16  = o_h16 + (size_t)NN * D / 2;
  const size_t o_res   = o_xl16 + (size_t)NN * D / 2;
  const size_t o_x2    = o_res + (size_t)NN * D;    // aliases cnt_p in prep
  const size_t o_xmid  = o_x2 + (size_t)NN * D;     // aliases rank in prep
  const size_t o_as    = o_xmid + (size_t)NN * D;   // NN*4
  const size_t o_ad    = o_as + (size_t)NN * 4;     // NN*4

  int*      rs    = (int*)(W + o_rs);
  float*    dinv  = W + o_dinv;
  float*    scal  = W + o_scal;
  int*      bsum  = (int*)(W + o_bsum);
  int*      boff  = (int*)(W + o_boff);
  float*    wea   = W + o_wea;
  uint_t*   grec  = (uint_t*)(W + o_grec);
  uint_t*   arec  = (uint_t*)(W + o_arec);
  ushort_t* h16   = (ushort_t*)(W + o_h16);
  ushort_t* xl16  = (ushort_t*)(W + o_xl16);
  float*    resb  = W + o_res;
  float*    x2b   = W + o_x2;
  float*    xmid  = W + o_xmid;
  float*    asb   = W + o_as;
  float*    adb   = W + o_ad;
  int*      cnt_p = (int*)x2b;   // prep alias (x2 first written after prep)
  int*      rank  = (int*)xmid;  // prep alias (xmid first written in layer 0 epilogue)

  const int B = 256;
  const int gN  = (NN + B - 1) / B;
  const int gE  = (NE + B - 1) / B;
  const int gNW = (NN * D + B - 1) / B;
  const int gRB = ((NN + RB - 1) / RB * 64 + B - 1) / B;

  hipMemsetAsync(cnt_p, 0, (size_t)NN * PAD * sizeof(int), stream);
  hipMemsetAsync(scal, 0, 1024 * sizeof(float), stream);
  k_histrank<<<gE, B, 0, stream>>>(ei, cnt_p, rank);
  k_scanA<<<gN, 256, 0, stream>>>(cnt_p, rs, bsum);
  k_scanB<<<1, 256, 0, stream>>>(bsum, boff);
  k_scanC<<<gN, B, 0, stream>>>(rs, boff);
  k_place<<<gE, B, 0, stream>>>(ei, ew, ea, rank, rs, grec, arec, scal);
  k_deg<<<gN, B, 0, stream>>>(grec, rs, dinv, scal);

  const float* xin = x;
  for (int l = 0; l < 2; ++l) {
    float* xout = (l == 0) ? xmid : (float*)d_out;
    k_dual_gemm<<<gRB, B, 0, stream>>>(xin, P[l][0], P[l][2], P[l][3], h16, resb, NN);
    k_gcn_agg<<<gNW, B, 0, stream>>>(h16, resb, dinv, rs, grec,
                                     P[l][1], P[l][4], P[l][5], x2b, NN);
    k_gat_node<<<gRB, B, 0, stream>>>(x2b, P[l][6], P[l][8], P[l][9],
                                      P[l][11], P[l][10], xl16, asb, adb, wea, NN);
    k_gat_agg<<<gNW, B, 0, stream>>>(xl16, x2b, asb, adb, rs, arec,
                                     wea, scal, P[l][7], xout, NN);
    xin = xout;
  }
}

// Round 6
// 429.505 us; speedup vs baseline: 2.4414x; 1.0531x over previous
//
#include <hip/hip_runtime.h>
#include <hip/hip_fp16.h>

#define NN 50000
#define NE 800000
#define D 64
#define EPS 1e-5f
#define PAD 16  // ints per counter slot -> one 64B line each
#define RB 8    // rows per wave in GEMM kernels (8 | 50000)

typedef unsigned short ushort_t;
typedef unsigned int uint_t;

__device__ __forceinline__ float wave_sum64(float v) {
#pragma unroll
  for (int m = 1; m <= 32; m <<= 1) v += __shfl_xor(v, m, 64);
  return v;
}
__device__ __forceinline__ float group_sum16(float v) {
#pragma unroll
  for (int m = 1; m <= 8; m <<= 1) v += __shfl_xor(v, m, 64);
  return v;
}
__device__ __forceinline__ float silu_f(float v) { return v / (1.f + __expf(-v)); }
__device__ __forceinline__ float lrelu_f(float v) { return v >= 0.f ? v : 0.2f * v; }
// bf16 pack (RNE) / unpack
__device__ __forceinline__ ushort_t f2b(float x) {
  unsigned u = __float_as_uint(x);
  return (ushort_t)((u + 0x7FFFu + ((u >> 16) & 1u)) >> 16);
}
__device__ __forceinline__ float b2f(ushort_t u) {
  return __uint_as_float(((unsigned)u) << 16);
}
// fp16 pack/unpack (edge payloads)
__device__ __forceinline__ ushort_t f2h(float x) {
  return __half_as_ushort(__float2half_rn(x));
}
__device__ __forceinline__ float h2f(unsigned u) {
  return __half2float(__ushort_as_half((ushort_t)(u & 0xFFFFu)));
}
__device__ __forceinline__ float sel4(float a, float b, float c, float d, int h) {
  float ab = (h & 1) ? b : a;
  float cd = (h & 1) ? d : c;
  return (h & 2) ? cd : ab;
}

// ---------- graph preprocessing ----------
// ONE device-atomic pass: rank[e] = arrival index within dst's segment.
__global__ void k_histrank(const int* __restrict__ ei, int* __restrict__ cnt_p,
                           int* __restrict__ rank) {
  int e = blockIdx.x * blockDim.x + threadIdx.x;
  if (e >= NE) return;
  int dst = ei[NE + e];
  rank[e] = atomicAdd(&cnt_p[(size_t)dst * PAD], 1);
}

__global__ void k_scanA(const int* __restrict__ cnt_p, int* __restrict__ rs,
                        int* __restrict__ bsum) {
  __shared__ int sm[256];
  int j = threadIdx.x, i = blockIdx.x * 256 + j;
  int v = (i < NN) ? cnt_p[(size_t)i * PAD] : 0;
  sm[j] = v;
  __syncthreads();
  for (int off = 1; off < 256; off <<= 1) {
    int t = (j >= off) ? sm[j - off] : 0;
    __syncthreads();
    sm[j] += t;
    __syncthreads();
  }
  if (i < NN) rs[i] = sm[j] - v;
  if (j == 255) bsum[blockIdx.x] = sm[255];
}

__global__ void k_scanB(const int* __restrict__ bsum, int* __restrict__ boff) {
  __shared__ int sm[256];
  int j = threadIdx.x;
  const int nb = (NN + 255) / 256;
  int v = (j < nb) ? bsum[j] : 0;
  sm[j] = v;
  __syncthreads();
  for (int off = 1; off < 256; off <<= 1) {
    int t = (j >= off) ? sm[j - off] : 0;
    __syncthreads();
    sm[j] += t;
    __syncthreads();
  }
  if (j < nb) boff[j] = sm[j] - v;
}

__global__ void k_scanC(int* __restrict__ rs, const int* __restrict__ boff) {
  int i = blockIdx.x * blockDim.x + threadIdx.x;
  if (i < NN) rs[i] = rs[i] + boff[i >> 8];
  if (i == 0) rs[NN] = NE;
}

// No atomics: slot = rs[dst] + rank[e]. ONE interleaved 8B record per edge:
//   rec[2*slot+0] = src | f16(ew)<<16   (GCN + deg)
//   rec[2*slot+1] = src | f16(ea)<<16   (GAT)
// -> one random 64B sector per edge instead of two.
__global__ void k_place(const int* __restrict__ ei, const float* __restrict__ ew,
                        const float* __restrict__ ea, const int* __restrict__ rank,
                        const int* __restrict__ rs,
                        uint2* __restrict__ rec, float* __restrict__ scal) {
  int e = blockIdx.x * blockDim.x + threadIdx.x;
  float a = 0.f;
  if (e < NE) {
    int src = ei[e];
    int dst = ei[NE + e];
    float w = ew[e];
    a = ea[e];
    int slot = rs[dst] + rank[e];
    uint2 r;
    r.x = (uint_t)(src & 0xFFFF) | ((uint_t)f2h(w) << 16);
    r.y = (uint_t)(src & 0xFFFF) | ((uint_t)f2h(a) << 16);
    rec[slot] = r;
  }
  float s = wave_sum64(a);
  if ((threadIdx.x & 63) == 0) {
    int slot = (blockIdx.x * 4 + (threadIdx.x >> 6)) & 63;
    atomicAdd(&scal[(size_t)slot * 16], s);
  }
}

// deg from CSR (contiguous reads); thread 0 finalizes mean edge_attr
__global__ void k_deg(const uint_t* __restrict__ rec, const int* __restrict__ rs,
                      float* __restrict__ dinv, float* __restrict__ scal) {
  int i = blockIdx.x * blockDim.x + threadIdx.x;
  if (i < NN) {
    float s = 1.f;  // self loop weight
    int k1 = rs[i + 1];
    for (int k = rs[i]; k < k1; ++k) s += h2f(rec[2 * k] >> 16);
    dinv[i] = rsqrtf(s);
  }
  if (i == 0) {
    float t = 0.f;
    for (int j = 0; j < 64; ++j) t += scal[(size_t)j * 16];
    scal[1] = t / (float)NE;
  }
}

// ---------- dense ops (8 rows per wave) ----------

__global__ void __launch_bounds__(256) k_dual_gemm(
    const float* __restrict__ x, const float* __restrict__ W1,
    const float* __restrict__ W2, const float* __restrict__ b2,
    ushort_t* __restrict__ out1, float* __restrict__ out2, int n) {
  int wv = (blockIdx.x * blockDim.x + threadIdx.x) >> 6;
  int c = threadIdx.x & 63;
  int r0 = wv * RB;
  if (r0 >= n) return;
  const float* xr = x + (size_t)r0 * D;
  float a1[RB] = {0.f, 0.f, 0.f, 0.f, 0.f, 0.f, 0.f, 0.f};
  float a2[RB] = {0.f, 0.f, 0.f, 0.f, 0.f, 0.f, 0.f, 0.f};
#pragma unroll 2
  for (int k = 0; k < D; k += 4) {
    float w10 = W1[(k + 0) * D + c], w11 = W1[(k + 1) * D + c];
    float w12 = W1[(k + 2) * D + c], w13 = W1[(k + 3) * D + c];
    float w20 = W2[(k + 0) * D + c], w21 = W2[(k + 1) * D + c];
    float w22 = W2[(k + 2) * D + c], w23 = W2[(k + 3) * D + c];
#pragma unroll
    for (int r = 0; r < RB; ++r) {
      float4 xv = *(const float4*)(xr + (size_t)r * D + k);
      a1[r] = fmaf(xv.x, w10, a1[r]); a2[r] = fmaf(xv.x, w20, a2[r]);
      a1[r] = fmaf(xv.y, w11, a1[r]); a2[r] = fmaf(xv.y, w21, a2[r]);
      a1[r] = fmaf(xv.z, w12, a1[r]); a2[r] = fmaf(xv.z, w22, a2[r]);
      a1[r] = fmaf(xv.w, w13, a1[r]); a2[r] = fmaf(xv.w, w23, a2[r]);
    }
  }
  float bb = b2[c];
#pragma unroll
  for (int r = 0; r < RB; ++r) {
    out1[(size_t)(r0 + r) * D + c] = f2b(a1[r]);
    out2[(size_t)(r0 + r) * D + c] = a2[r] + bb;
  }
}

__global__ void __launch_bounds__(256) k_gat_node(
    const float* __restrict__ x2, const float* __restrict__ Wg,
    const float* __restrict__ att_src, const float* __restrict__ att_dst,
    const float* __restrict__ We, const float* __restrict__ a_e,
    ushort_t* __restrict__ xl, float* __restrict__ a_s, float* __restrict__ a_d,
    float* __restrict__ wea, int n) {
  if (blockIdx.x == 0 && threadIdx.x < 64) {
    int c = threadIdx.x;
    float v = group_sum16(We[c] * a_e[c]);
    if ((c & 15) == 0) wea[c >> 4] = v;
  }
  int wv = (blockIdx.x * blockDim.x + threadIdx.x) >> 6;
  int c = threadIdx.x & 63;
  int r0 = wv * RB;
  if (r0 >= n) return;
  const float* xr = x2 + (size_t)r0 * D;
  float acc[RB] = {0.f, 0.f, 0.f, 0.f, 0.f, 0.f, 0.f, 0.f};
#pragma unroll 2
  for (int k = 0; k < D; k += 4) {
    float w0 = Wg[(k + 0) * D + c], w1 = Wg[(k + 1) * D + c];
    float w2 = Wg[(k + 2) * D + c], w3 = Wg[(k + 3) * D + c];
#pragma unroll
    for (int r = 0; r < RB; ++r) {
      float4 xv = *(const float4*)(xr + (size_t)r * D + k);
      acc[r] = fmaf(xv.x, w0, acc[r]);
      acc[r] = fmaf(xv.y, w1, acc[r]);
      acc[r] = fmaf(xv.z, w2, acc[r]);
      acc[r] = fmaf(xv.w, w3, acc[r]);
    }
  }
  float asv = att_src[c], adv = att_dst[c];
#pragma unroll
  for (int r = 0; r < RB; ++r) {
    xl[(size_t)(r0 + r) * D + c] = f2b(acc[r]);
    float vs = group_sum16(acc[r] * asv);
    float vd = group_sum16(acc[r] * adv);
    if ((c & 15) == 0) {
      a_s[(size_t)(r0 + r) * 4 + (c >> 4)] = vs;
      a_d[(size_t)(r0 + r) * 4 + (c >> 4)] = vd;
    }
  }
}

// GCN aggregate + bias + silu + residual + LayerNorm. One wave per node.
// 8-wide gather unroll for memory-level parallelism.
__global__ void __launch_bounds__(256) k_gcn_agg(
    const ushort_t* __restrict__ h16, const float* __restrict__ res,
    const float* __restrict__ dinv, const int* __restrict__ rs,
    const uint_t* __restrict__ rec,
    const float* __restrict__ gb, const float* __restrict__ lg, const float* __restrict__ lb,
    float* __restrict__ x2, int n) {
  __shared__ int   ss[4][64];
  __shared__ float swt[4][64];
  int w = threadIdx.x >> 6;
  int i = (blockIdx.x * blockDim.x + threadIdx.x) >> 6;
  int c = threadIdx.x & 63;
  if (i >= n) return;
  float di = dinv[i];
  float acc = di * di * b2f(h16[(size_t)i * D + c]);
  int k0 = rs[i], k1 = rs[i + 1];
  for (int base = k0; base < k1; base += 64) {
    int cnt = min(64, k1 - base);
    int src = 0; float wn = 0.f;
    if (c < cnt) {
      uint_t r = rec[2 * (size_t)(base + c)];
      src = (int)(r & 0xFFFFu);
      wn = dinv[src] * h2f(r >> 16) * di;
    }
    ss[w][c] = src;
    swt[w][c] = wn;
    int cnt8 = (cnt + 7) & ~7;
    for (int j = 0; j < cnt8; j += 8) {
      int4 sa = *(const int4*)&ss[w][j];
      int4 sb = *(const int4*)&ss[w][j + 4];
      float4 wa = *(const float4*)&swt[w][j];
      float4 wb = *(const float4*)&swt[w][j + 4];
      float x0 = b2f(h16[(size_t)sa.x * D + c]);
      float x1 = b2f(h16[(size_t)sa.y * D + c]);
      float x2v = b2f(h16[(size_t)sa.z * D + c]);
      float x3 = b2f(h16[(size_t)sa.w * D + c]);
      float x4 = b2f(h16[(size_t)sb.x * D + c]);
      float x5 = b2f(h16[(size_t)sb.y * D + c]);
      float x6 = b2f(h16[(size_t)sb.z * D + c]);
      float x7 = b2f(h16[(size_t)sb.w * D + c]);
      acc = fmaf(wa.x, x0, acc);
      acc = fmaf(wa.y, x1, acc);
      acc = fmaf(wa.z, x2v, acc);
      acc = fmaf(wa.w, x3, acc);
      acc = fmaf(wb.x, x4, acc);
      acc = fmaf(wb.y, x5, acc);
      acc = fmaf(wb.z, x6, acc);
      acc = fmaf(wb.w, x7, acc);
    }
  }
  float v = acc + gb[c];
  float x1 = silu_f(v) + res[(size_t)i * D + c];
  float mu = wave_sum64(x1) * (1.f / 64.f);
  float d = x1 - mu;
  float var = wave_sum64(d * d) * (1.f / 64.f);
  x2[(size_t)i * D + c] = d * rsqrtf(var + EPS) * lg[c] + lb[c];
}

// GAT aggregate, no-max softmax, stage lane computes per-edge head exps once;
// 8-wide gather unroll.
__global__ void __launch_bounds__(256) k_gat_agg(
    const ushort_t* __restrict__ xl16, const float* __restrict__ x2,
    const float* __restrict__ a_s, const float* __restrict__ a_d,
    const int* __restrict__ rs, const uint_t* __restrict__ rec,
    const float* __restrict__ wea, const float* __restrict__ scal,
    const float* __restrict__ bg, float* __restrict__ xout, int n) {
  __shared__ int   ss[4][64];
  __shared__ float el[4][4][68];
  int w = threadIdx.x >> 6;
  int i = (blockIdx.x * blockDim.x + threadIdx.x) >> 6;
  int l = threadIdx.x & 63;
  if (i >= n) return;
  int hh = l >> 4;
  float4 ad4 = *(const float4*)(a_d + (size_t)i * 4);
  float4 wv4 = *(const float4*)wea;
  float mean_attr = scal[1];
  float ad_h = sel4(ad4.x, ad4.y, ad4.z, ad4.w, hh);
  float we_h = sel4(wv4.x, wv4.y, wv4.z, wv4.w, hh);
  float as_i = a_s[(size_t)i * 4 + hh];
  float e_self = __expf(lrelu_f(as_i + ad_h + mean_attr * we_h));
  float s_acc = e_self;
  float acc = e_self * b2f(xl16[(size_t)i * D + l]);
  int k0 = rs[i], k1 = rs[i + 1];
  for (int base = k0; base < k1; base += 64) {
    int cnt = min(64, k1 - base);
    int src = 0;
    float e0v = 0.f, e1v = 0.f, e2v = 0.f, e3v = 0.f;
    if (l < cnt) {
      uint_t r = rec[2 * (size_t)(base + l) + 1];
      src = (int)(r & 0xFFFFu);
      float ea = h2f(r >> 16);
      float4 as4 = *(const float4*)(a_s + (size_t)src * 4);
      e0v = __expf(lrelu_f(as4.x + fmaf(ea, wv4.x, ad4.x)));
      e1v = __expf(lrelu_f(as4.y + fmaf(ea, wv4.y, ad4.y)));
      e2v = __expf(lrelu_f(as4.z + fmaf(ea, wv4.z, ad4.z)));
      e3v = __expf(lrelu_f(as4.w + fmaf(ea, wv4.w, ad4.w)));
    }
    ss[w][l] = src;
    el[w][0][l] = e0v;
    el[w][1][l] = e1v;
    el[w][2][l] = e2v;
    el[w][3][l] = e3v;
    int cnt8 = (cnt + 7) & ~7;
    for (int j = 0; j < cnt8; j += 8) {
      int4 sa = *(const int4*)&ss[w][j];
      int4 sb = *(const int4*)&ss[w][j + 4];
      float4 ea4 = *(const float4*)&el[w][hh][j];
      float4 eb4 = *(const float4*)&el[w][hh][j + 4];
      float x0 = b2f(xl16[(size_t)sa.x * D + l]);
      float x1 = b2f(xl16[(size_t)sa.y * D + l]);
      float x2v = b2f(xl16[(size_t)sa.z * D + l]);
      float x3 = b2f(xl16[(size_t)sa.w * D + l]);
      float x4 = b2f(xl16[(size_t)sb.x * D + l]);
      float x5 = b2f(xl16[(size_t)sb.y * D + l]);
      float x6 = b2f(xl16[(size_t)sb.z * D + l]);
      float x7 = b2f(xl16[(size_t)sb.w * D + l]);
      acc = fmaf(ea4.x, x0, acc);
      acc = fmaf(ea4.y, x1, acc);
      acc = fmaf(ea4.z, x2v, acc);
      acc = fmaf(ea4.w, x3, acc);
      acc = fmaf(eb4.x, x4, acc);
      acc = fmaf(eb4.y, x5, acc);
      acc = fmaf(eb4.z, x6, acc);
      acc = fmaf(eb4.w, x7, acc);
      s_acc += ((ea4.x + ea4.y) + (ea4.z + ea4.w)) +
               ((eb4.x + eb4.y) + (eb4.z + eb4.w));
    }
  }
  float o = acc / (s_acc + 1e-16f) + bg[l];
  xout[(size_t)i * D + l] = silu_f(o) + x2[(size_t)i * D + l];
}

// ---------- launch ----------

extern "C" void kernel_launch(void* const* d_in, const int* in_sizes, int n_in,
                              void* d_out, int out_size, void* d_ws, size_t ws_size,
                              hipStream_t stream) {
  (void)in_sizes; (void)n_in; (void)out_size; (void)ws_size;
  const float* x  = (const float*)d_in[0];
  const int*   ei = (const int*)d_in[1];
  const float* ew = (const float*)d_in[2];
  const float* ea = (const float*)d_in[3];
  const float* P[2][12];
  for (int l = 0; l < 2; ++l)
    for (int j = 0; j < 12; ++j) P[l][j] = (const float*)d_in[4 + l * 12 + j];

  float* W = (float*)d_ws;
  // layout in float units (offsets multiples of 16 -> 16B alignment everywhere)
  const size_t o_rs    = 0;                          // NN+16 ints
  const size_t o_dinv  = o_rs + NN + 16;             // NN
  const size_t o_bsum  = o_dinv + NN;                // 256
  const size_t o_boff  = o_bsum + 256;               // 256
  const size_t o_wea   = o_boff + 256;               // 16
  const size_t o_scal  = o_wea + 16;                 // 1024  (contiguous with cnt_p:
  const size_t o_cnt   = o_scal + 1024;              // NN*PAD ints -> one memset)
  const size_t o_rec   = o_cnt + (size_t)NN * PAD;   // NE uint2 = 2*NE floats
  const size_t o_h16   = o_rec + (size_t)NE * 2;     // NN*D ushort
  const size_t o_xl16  = o_h16 + (size_t)NN * D / 2;
  const size_t o_res   = o_xl16 + (size_t)NN * D / 2;
  const size_t o_x2    = o_res + (size_t)NN * D;
  const size_t o_xmid  = o_x2 + (size_t)NN * D;      // aliases rank in prep
  const size_t o_as    = o_xmid + (size_t)NN * D;    // NN*4
  const size_t o_ad    = o_as + (size_t)NN * 4;      // NN*4

  int*      rs    = (int*)(W + o_rs);
  float*    dinv  = W + o_dinv;
  int*      bsum  = (int*)(W + o_bsum);
  int*      boff  = (int*)(W + o_boff);
  float*    wea   = W + o_wea;
  float*    scal  = W + o_scal;
  int*      cnt_p = (int*)(W + o_cnt);
  uint2*    rec   = (uint2*)(W + o_rec);
  ushort_t* h16   = (ushort_t*)(W + o_h16);
  ushort_t* xl16  = (ushort_t*)(W + o_xl16);
  float*    resb  = W + o_res;
  float*    x2b   = W + o_x2;
  float*    xmid  = W + o_xmid;
  float*    asb   = W + o_as;
  float*    adb   = W + o_ad;
  int*      rank  = (int*)xmid;  // prep alias (xmid first written in layer-0 epilogue)

  const int B = 256;
  const int gN  = (NN + B - 1) / B;
  const int gE  = (NE + B - 1) / B;
  const int gNW = (NN * D + B - 1) / B;
  const int gRB = ((NN + RB - 1) / RB * 64 + B - 1) / B;

  // one memset covers scal (4KB) + cnt_p (3.2MB), contiguous
  hipMemsetAsync(W + o_scal, 0, (1024 + (size_t)NN * PAD) * sizeof(float), stream);
  k_histrank<<<gE, B, 0, stream>>>(ei, cnt_p, rank);
  k_scanA<<<gN, 256, 0, stream>>>(cnt_p, rs, bsum);
  k_scanB<<<1, 256, 0, stream>>>(bsum, boff);
  k_scanC<<<gN, B, 0, stream>>>(rs, boff);
  k_place<<<gE, B, 0, stream>>>(ei, ew, ea, rank, rs, rec, scal);
  k_deg<<<gN, B, 0, stream>>>((const uint_t*)rec, rs, dinv, scal);

  const float* xin = x;
  for (int l = 0; l < 2; ++l) {
    float* xout = (l == 0) ? xmid : (float*)d_out;
    k_dual_gemm<<<gRB, B, 0, stream>>>(xin, P[l][0], P[l][2], P[l][3], h16, resb, NN);
    k_gcn_agg<<<gNW, B, 0, stream>>>(h16, resb, dinv, rs, (const uint_t*)rec,
                                     P[l][1], P[l][4], P[l][5], x2b, NN);
    k_gat_node<<<gRB, B, 0, stream>>>(x2b, P[l][6], P[l][8], P[l][9],
                                      P[l][11], P[l][10], xl16, asb, adb, wea, NN);
    k_gat_agg<<<gNW, B, 0, stream>>>(xl16, x2b, asb, adb, rs, (const uint_t*)rec,
                                     wea, scal, P[l][7], xout, NN);
    xin = xout;
  }
}

// Round 7
// 344.031 us; speedup vs baseline: 3.0480x; 1.2484x over previous
//
#include <hip/hip_runtime.h>
#include <hip/hip_fp16.h>

#define NN 50000
#define NE 800000
#define D 64
#define EPS 1e-5f
#define PAD 16   // ints per counter slot -> one 64B line each
#define NT 3125  // NN/16 row-tiles for MFMA GEMMs

typedef unsigned short ushort_t;
typedef unsigned int uint_t;
typedef __attribute__((ext_vector_type(8))) short bf16x8;
typedef __attribute__((ext_vector_type(4))) float f32x4;

__device__ __forceinline__ float wave_sum64(float v) {
#pragma unroll
  for (int m = 1; m <= 32; m <<= 1) v += __shfl_xor(v, m, 64);
  return v;
}
__device__ __forceinline__ float group_sum16(float v) {
#pragma unroll
  for (int m = 1; m <= 8; m <<= 1) v += __shfl_xor(v, m, 64);
  return v;
}
__device__ __forceinline__ float silu_f(float v) { return v / (1.f + __expf(-v)); }
__device__ __forceinline__ float lrelu_f(float v) { return v >= 0.f ? v : 0.2f * v; }
__device__ __forceinline__ ushort_t f2b(float x) {
  unsigned u = __float_as_uint(x);
  return (ushort_t)((u + 0x7FFFu + ((u >> 16) & 1u)) >> 16);
}
__device__ __forceinline__ float b2f(ushort_t u) {
  return __uint_as_float(((unsigned)u) << 16);
}
__device__ __forceinline__ ushort_t f2h(float x) {
  return __half_as_ushort(__float2half_rn(x));
}
__device__ __forceinline__ float h2f(unsigned u) {
  return __half2float(__ushort_as_half((ushort_t)(u & 0xFFFFu)));
}
__device__ __forceinline__ float sel4(float a, float b, float c, float d, int h) {
  float ab = (h & 1) ? b : a;
  float cd = (h & 1) ? d : c;
  return (h & 2) ? cd : ab;
}
__device__ __forceinline__ bf16x8 pack8(float4 a, float4 b) {
  bf16x8 r;
  r[0] = (short)f2b(a.x); r[1] = (short)f2b(a.y);
  r[2] = (short)f2b(a.z); r[3] = (short)f2b(a.w);
  r[4] = (short)f2b(b.x); r[5] = (short)f2b(b.y);
  r[6] = (short)f2b(b.z); r[7] = (short)f2b(b.w);
  return r;
}

// ---------- graph preprocessing ----------
__global__ void k_histrank(const int* __restrict__ ei, int* __restrict__ cnt_p,
                           int* __restrict__ rank) {
  int e = blockIdx.x * blockDim.x + threadIdx.x;
  if (e >= NE) return;
  int dst = ei[NE + e];
  rank[e] = atomicAdd(&cnt_p[(size_t)dst * PAD], 1);
}

__global__ void k_scanA(const int* __restrict__ cnt_p, int* __restrict__ rs,
                        int* __restrict__ bsum) {
  __shared__ int sm[256];
  int j = threadIdx.x, i = blockIdx.x * 256 + j;
  int v = (i < NN) ? cnt_p[(size_t)i * PAD] : 0;
  sm[j] = v;
  __syncthreads();
  for (int off = 1; off < 256; off <<= 1) {
    int t = (j >= off) ? sm[j - off] : 0;
    __syncthreads();
    sm[j] += t;
    __syncthreads();
  }
  if (i < NN) rs[i] = sm[j] - v;
  if (j == 255) bsum[blockIdx.x] = sm[255];
}

__global__ void k_scanB(const int* __restrict__ bsum, int* __restrict__ boff) {
  __shared__ int sm[256];
  int j = threadIdx.x;
  const int nb = (NN + 255) / 256;
  int v = (j < nb) ? bsum[j] : 0;
  sm[j] = v;
  __syncthreads();
  for (int off = 1; off < 256; off <<= 1) {
    int t = (j >= off) ? sm[j - off] : 0;
    __syncthreads();
    sm[j] += t;
    __syncthreads();
  }
  if (j < nb) boff[j] = sm[j] - v;
}

__global__ void k_scanC(int* __restrict__ rs, const int* __restrict__ boff) {
  int i = blockIdx.x * blockDim.x + threadIdx.x;
  if (i < NN) rs[i] = rs[i] + boff[i >> 8];
  if (i == 0) rs[NN] = NE;
}

__global__ void k_place(const int* __restrict__ ei, const float* __restrict__ ew,
                        const float* __restrict__ ea, const int* __restrict__ rank,
                        const int* __restrict__ rs,
                        uint2* __restrict__ rec, float* __restrict__ scal) {
  int e = blockIdx.x * blockDim.x + threadIdx.x;
  float a = 0.f;
  if (e < NE) {
    int src = ei[e];
    int dst = ei[NE + e];
    float w = ew[e];
    a = ea[e];
    int slot = rs[dst] + rank[e];
    uint2 r;
    r.x = (uint_t)(src & 0xFFFF) | ((uint_t)f2h(w) << 16);
    r.y = (uint_t)(src & 0xFFFF) | ((uint_t)f2h(a) << 16);
    rec[slot] = r;
  }
  float s = wave_sum64(a);
  if ((threadIdx.x & 63) == 0) {
    int slot = (blockIdx.x * 4 + (threadIdx.x >> 6)) & 63;
    atomicAdd(&scal[(size_t)slot * 16], s);
  }
}

__global__ void k_deg(const uint_t* __restrict__ rec, const int* __restrict__ rs,
                      float* __restrict__ dinv, float* __restrict__ scal) {
  int i = blockIdx.x * blockDim.x + threadIdx.x;
  if (i < NN) {
    float s = 1.f;
    int k1 = rs[i + 1];
    for (int k = rs[i]; k < k1; ++k) s += h2f(rec[2 * k] >> 16);
    dinv[i] = rsqrtf(s);
  }
  if (i == 0) {
    float t = 0.f;
    for (int j = 0; j < 64; ++j) t += scal[(size_t)j * 16];
    scal[1] = t / (float)NE;
  }
}

// ---------- MFMA dense ops ----------
// Per block: swizzle W1,W2 into LDS as B-fragments (bf16). Per wave: one
// 16-row tile; A-frags cvt'd fp32->bf16; 16 mfma_f32_16x16x32_bf16.
// Frag layouts (verified, guide §3): A[m=lane&15][k=quad*8+j];
// B[k=quad*8+j][n=lane&15]; C/D col=lane&15, row=quad*4+reg.
__global__ void __launch_bounds__(256) k_dual_gemm(
    const float* __restrict__ x, const float* __restrict__ W1,
    const float* __restrict__ W2, const float* __restrict__ b2,
    ushort_t* __restrict__ out1, float* __restrict__ out2) {
  __shared__ ushort_t wf[2 * 2 * 4 * 512];  // [mat][kstep][ntile][lane*8+j]
  for (int e = threadIdx.x; e < 8192; e += 256) {
    int f = e >> 9, r = e & 511;
    int lane = r >> 3, j = r & 7;
    int m = f >> 3, s = (f >> 2) & 1, t = f & 3;
    int k = s * 32 + (lane >> 4) * 8 + j;
    int n = t * 16 + (lane & 15);
    const float* Wm = m ? W2 : W1;
    wf[e] = f2b(Wm[k * D + n]);
  }
  __syncthreads();
  int tile = blockIdx.x * 4 + (threadIdx.x >> 6);
  if (tile >= NT) return;
  int l = threadIdx.x & 63;
  int q = l >> 4, cn = l & 15;
  const float* xr = x + ((size_t)tile * 16 + cn) * D + q * 8;
  float4 xa = *(const float4*)xr;
  float4 xb = *(const float4*)(xr + 4);
  float4 xc = *(const float4*)(xr + 32);
  float4 xd = *(const float4*)(xr + 36);
  bf16x8 a0 = pack8(xa, xb), a1 = pack8(xc, xd);
  f32x4 acc1[4], acc2[4];
#pragma unroll
  for (int t = 0; t < 4; ++t) {
    bf16x8 b10 = *(const bf16x8*)&wf[(0 * 8 + 0 * 4 + t) * 512 + l * 8];
    bf16x8 b11 = *(const bf16x8*)&wf[(0 * 8 + 1 * 4 + t) * 512 + l * 8];
    bf16x8 b20 = *(const bf16x8*)&wf[(1 * 8 + 0 * 4 + t) * 512 + l * 8];
    bf16x8 b21 = *(const bf16x8*)&wf[(1 * 8 + 1 * 4 + t) * 512 + l * 8];
    f32x4 z = {0.f, 0.f, 0.f, 0.f};
    acc1[t] = __builtin_amdgcn_mfma_f32_16x16x32_bf16(a0, b10, z, 0, 0, 0);
    acc1[t] = __builtin_amdgcn_mfma_f32_16x16x32_bf16(a1, b11, acc1[t], 0, 0, 0);
    acc2[t] = __builtin_amdgcn_mfma_f32_16x16x32_bf16(a0, b20, z, 0, 0, 0);
    acc2[t] = __builtin_amdgcn_mfma_f32_16x16x32_bf16(a1, b21, acc2[t], 0, 0, 0);
  }
#pragma unroll
  for (int t = 0; t < 4; ++t) {
    float bb = b2[t * 16 + cn];
#pragma unroll
    for (int r = 0; r < 4; ++r) {
      size_t row = (size_t)tile * 16 + q * 4 + r;
      out1[row * D + t * 16 + cn] = f2b(acc1[t][r]);
      out2[row * D + t * 16 + cn] = acc2[t][r] + bb;
    }
  }
}

// xl16 = bf16(x2 @ Wg); a_s/a_d per head from C-frags (head == n-tile).
__global__ void __launch_bounds__(256) k_gat_node(
    const float* __restrict__ x2, const float* __restrict__ Wg,
    const float* __restrict__ att_src, const float* __restrict__ att_dst,
    const float* __restrict__ We, const float* __restrict__ a_e,
    ushort_t* __restrict__ xl, float* __restrict__ a_s, float* __restrict__ a_d,
    float* __restrict__ wea) {
  __shared__ ushort_t wf[2 * 4 * 512];  // [kstep][ntile][lane*8+j]
  for (int e = threadIdx.x; e < 4096; e += 256) {
    int f = e >> 9, r = e & 511;
    int lane = r >> 3, j = r & 7;
    int s = (f >> 2) & 1, t = f & 3;
    int k = s * 32 + (lane >> 4) * 8 + j;
    int n = t * 16 + (lane & 15);
    wf[e] = f2b(Wg[k * D + n]);
  }
  __syncthreads();
  if (blockIdx.x == 0 && threadIdx.x < 64) {
    int c = threadIdx.x;
    float v = group_sum16(We[c] * a_e[c]);
    if ((c & 15) == 0) wea[c >> 4] = v;
  }
  int tile = blockIdx.x * 4 + (threadIdx.x >> 6);
  if (tile >= NT) return;
  int l = threadIdx.x & 63;
  int q = l >> 4, cn = l & 15;
  const float* xr = x2 + ((size_t)tile * 16 + cn) * D + q * 8;
  float4 xa = *(const float4*)xr;
  float4 xb = *(const float4*)(xr + 4);
  float4 xc = *(const float4*)(xr + 32);
  float4 xd = *(const float4*)(xr + 36);
  bf16x8 a0 = pack8(xa, xb), a1 = pack8(xc, xd);
  f32x4 acc[4];
#pragma unroll
  for (int t = 0; t < 4; ++t) {
    bf16x8 b0 = *(const bf16x8*)&wf[(0 * 4 + t) * 512 + l * 8];
    bf16x8 b1 = *(const bf16x8*)&wf[(1 * 4 + t) * 512 + l * 8];
    f32x4 z = {0.f, 0.f, 0.f, 0.f};
    acc[t] = __builtin_amdgcn_mfma_f32_16x16x32_bf16(a0, b0, z, 0, 0, 0);
    acc[t] = __builtin_amdgcn_mfma_f32_16x16x32_bf16(a1, b1, acc[t], 0, 0, 0);
  }
#pragma unroll
  for (int t = 0; t < 4; ++t) {
    float av = att_src[t * 16 + cn];
    float dv = att_dst[t * 16 + cn];
#pragma unroll
    for (int r = 0; r < 4; ++r) {
      size_t row = (size_t)tile * 16 + q * 4 + r;
      xl[row * D + t * 16 + cn] = f2b(acc[t][r]);
      float vs = group_sum16(acc[t][r] * av);
      float vd = group_sum16(acc[t][r] * dv);
      if (cn == 0) {
        a_s[row * 4 + t] = vs;
        a_d[row * 4 + t] = vd;
      }
    }
  }
}

// ---------- aggregation kernels (unchanged from R6) ----------
__global__ void __launch_bounds__(256) k_gcn_agg(
    const ushort_t* __restrict__ h16, const float* __restrict__ res,
    const float* __restrict__ dinv, const int* __restrict__ rs,
    const uint_t* __restrict__ rec,
    const float* __restrict__ gb, const float* __restrict__ lg, const float* __restrict__ lb,
    float* __restrict__ x2, int n) {
  __shared__ int   ss[4][64];
  __shared__ float swt[4][64];
  int w = threadIdx.x >> 6;
  int i = (blockIdx.x * blockDim.x + threadIdx.x) >> 6;
  int c = threadIdx.x & 63;
  if (i >= n) return;
  float di = dinv[i];
  float acc = di * di * b2f(h16[(size_t)i * D + c]);
  int k0 = rs[i], k1 = rs[i + 1];
  for (int base = k0; base < k1; base += 64) {
    int cnt = min(64, k1 - base);
    int src = 0; float wn = 0.f;
    if (c < cnt) {
      uint_t r = rec[2 * (size_t)(base + c)];
      src = (int)(r & 0xFFFFu);
      wn = dinv[src] * h2f(r >> 16) * di;
    }
    ss[w][c] = src;
    swt[w][c] = wn;
    int cnt8 = (cnt + 7) & ~7;
    for (int j = 0; j < cnt8; j += 8) {
      int4 sa = *(const int4*)&ss[w][j];
      int4 sb = *(const int4*)&ss[w][j + 4];
      float4 wa = *(const float4*)&swt[w][j];
      float4 wb = *(const float4*)&swt[w][j + 4];
      float x0 = b2f(h16[(size_t)sa.x * D + c]);
      float x1 = b2f(h16[(size_t)sa.y * D + c]);
      float x2v = b2f(h16[(size_t)sa.z * D + c]);
      float x3 = b2f(h16[(size_t)sa.w * D + c]);
      float x4 = b2f(h16[(size_t)sb.x * D + c]);
      float x5 = b2f(h16[(size_t)sb.y * D + c]);
      float x6 = b2f(h16[(size_t)sb.z * D + c]);
      float x7 = b2f(h16[(size_t)sb.w * D + c]);
      acc = fmaf(wa.x, x0, acc);
      acc = fmaf(wa.y, x1, acc);
      acc = fmaf(wa.z, x2v, acc);
      acc = fmaf(wa.w, x3, acc);
      acc = fmaf(wb.x, x4, acc);
      acc = fmaf(wb.y, x5, acc);
      acc = fmaf(wb.z, x6, acc);
      acc = fmaf(wb.w, x7, acc);
    }
  }
  float v = acc + gb[c];
  float x1 = silu_f(v) + res[(size_t)i * D + c];
  float mu = wave_sum64(x1) * (1.f / 64.f);
  float d = x1 - mu;
  float var = wave_sum64(d * d) * (1.f / 64.f);
  x2[(size_t)i * D + c] = d * rsqrtf(var + EPS) * lg[c] + lb[c];
}

__global__ void __launch_bounds__(256) k_gat_agg(
    const ushort_t* __restrict__ xl16, const float* __restrict__ x2,
    const float* __restrict__ a_s, const float* __restrict__ a_d,
    const int* __restrict__ rs, const uint_t* __restrict__ rec,
    const float* __restrict__ wea, const float* __restrict__ scal,
    const float* __restrict__ bg, float* __restrict__ xout, int n) {
  __shared__ int   ss[4][64];
  __shared__ float el[4][4][68];
  int w = threadIdx.x >> 6;
  int i = (blockIdx.x * blockDim.x + threadIdx.x) >> 6;
  int l = threadIdx.x & 63;
  if (i >= n) return;
  int hh = l >> 4;
  float4 ad4 = *(const float4*)(a_d + (size_t)i * 4);
  float4 wv4 = *(const float4*)wea;
  float mean_attr = scal[1];
  float ad_h = sel4(ad4.x, ad4.y, ad4.z, ad4.w, hh);
  float we_h = sel4(wv4.x, wv4.y, wv4.z, wv4.w, hh);
  float as_i = a_s[(size_t)i * 4 + hh];
  float e_self = __expf(lrelu_f(as_i + ad_h + mean_attr * we_h));
  float s_acc = e_self;
  float acc = e_self * b2f(xl16[(size_t)i * D + l]);
  int k0 = rs[i], k1 = rs[i + 1];
  for (int base = k0; base < k1; base += 64) {
    int cnt = min(64, k1 - base);
    int src = 0;
    float e0v = 0.f, e1v = 0.f, e2v = 0.f, e3v = 0.f;
    if (l < cnt) {
      uint_t r = rec[2 * (size_t)(base + l) + 1];
      src = (int)(r & 0xFFFFu);
      float ea = h2f(r >> 16);
      float4 as4 = *(const float4*)(a_s + (size_t)src * 4);
      e0v = __expf(lrelu_f(as4.x + fmaf(ea, wv4.x, ad4.x)));
      e1v = __expf(lrelu_f(as4.y + fmaf(ea, wv4.y, ad4.y)));
      e2v = __expf(lrelu_f(as4.z + fmaf(ea, wv4.z, ad4.z)));
      e3v = __expf(lrelu_f(as4.w + fmaf(ea, wv4.w, ad4.w)));
    }
    ss[w][l] = src;
    el[w][0][l] = e0v;
    el[w][1][l] = e1v;
    el[w][2][l] = e2v;
    el[w][3][l] = e3v;
    int cnt8 = (cnt + 7) & ~7;
    for (int j = 0; j < cnt8; j += 8) {
      int4 sa = *(const int4*)&ss[w][j];
      int4 sb = *(const int4*)&ss[w][j + 4];
      float4 ea4 = *(const float4*)&el[w][hh][j];
      float4 eb4 = *(const float4*)&el[w][hh][j + 4];
      float x0 = b2f(xl16[(size_t)sa.x * D + l]);
      float x1 = b2f(xl16[(size_t)sa.y * D + l]);
      float x2v = b2f(xl16[(size_t)sa.z * D + l]);
      float x3 = b2f(xl16[(size_t)sa.w * D + l]);
      float x4 = b2f(xl16[(size_t)sb.x * D + l]);
      float x5 = b2f(xl16[(size_t)sb.y * D + l]);
      float x6 = b2f(xl16[(size_t)sb.z * D + l]);
      float x7 = b2f(xl16[(size_t)sb.w * D + l]);
      acc = fmaf(ea4.x, x0, acc);
      acc = fmaf(ea4.y, x1, acc);
      acc = fmaf(ea4.z, x2v, acc);
      acc = fmaf(ea4.w, x3, acc);
      acc = fmaf(eb4.x, x4, acc);
      acc = fmaf(eb4.y, x5, acc);
      acc = fmaf(eb4.z, x6, acc);
      acc = fmaf(eb4.w, x7, acc);
      s_acc += ((ea4.x + ea4.y) + (ea4.z + ea4.w)) +
               ((eb4.x + eb4.y) + (eb4.z + eb4.w));
    }
  }
  float o = acc / (s_acc + 1e-16f) + bg[l];
  xout[(size_t)i * D + l] = silu_f(o) + x2[(size_t)i * D + l];
}

// ---------- launch ----------

extern "C" void kernel_launch(void* const* d_in, const int* in_sizes, int n_in,
                              void* d_out, int out_size, void* d_ws, size_t ws_size,
                              hipStream_t stream) {
  (void)in_sizes; (void)n_in; (void)out_size; (void)ws_size;
  const float* x  = (const float*)d_in[0];
  const int*   ei = (const int*)d_in[1];
  const float* ew = (const float*)d_in[2];
  const float* ea = (const float*)d_in[3];
  const float* P[2][12];
  for (int l = 0; l < 2; ++l)
    for (int j = 0; j < 12; ++j) P[l][j] = (const float*)d_in[4 + l * 12 + j];

  float* W = (float*)d_ws;
  const size_t o_rs    = 0;                          // NN+16 ints
  const size_t o_dinv  = o_rs + NN + 16;             // NN
  const size_t o_bsum  = o_dinv + NN;                // 256
  const size_t o_boff  = o_bsum + 256;               // 256
  const size_t o_wea   = o_boff + 256;               // 16
  const size_t o_scal  = o_wea + 16;                 // 1024 (contiguous w/ cnt_p)
  const size_t o_cnt   = o_scal + 1024;              // NN*PAD ints
  const size_t o_rec   = o_cnt + (size_t)NN * PAD;   // NE uint2
  const size_t o_h16   = o_rec + (size_t)NE * 2;     // NN*D ushort
  const size_t o_xl16  = o_h16 + (size_t)NN * D / 2;
  const size_t o_res   = o_xl16 + (size_t)NN * D / 2;
  const size_t o_x2    = o_res + (size_t)NN * D;
  const size_t o_xmid  = o_x2 + (size_t)NN * D;      // aliases rank in prep
  const size_t o_as    = o_xmid + (size_t)NN * D;    // NN*4
  const size_t o_ad    = o_as + (size_t)NN * 4;      // NN*4

  int*      rs    = (int*)(W + o_rs);
  float*    dinv  = W + o_dinv;
  int*      bsum  = (int*)(W + o_bsum);
  int*      boff  = (int*)(W + o_boff);
  float*    wea   = W + o_wea;
  float*    scal  = W + o_scal;
  int*      cnt_p = (int*)(W + o_cnt);
  uint2*    rec   = (uint2*)(W + o_rec);
  ushort_t* h16   = (ushort_t*)(W + o_h16);
  ushort_t* xl16  = (ushort_t*)(W + o_xl16);
  float*    resb  = W + o_res;
  float*    x2b   = W + o_x2;
  float*    xmid  = W + o_xmid;
  float*    asb   = W + o_as;
  float*    adb   = W + o_ad;
  int*      rank  = (int*)xmid;  // prep alias

  const int B = 256;
  const int gN  = (NN + B - 1) / B;
  const int gE  = (NE + B - 1) / B;
  const int gNW = (NN * D + B - 1) / B;   // wave per node (agg kernels)
  const int gMF = (NT + 3) / 4;           // 4 tiles (waves) per block

  hipMemsetAsync(W + o_scal, 0, (1024 + (size_t)NN * PAD) * sizeof(float), stream);
  k_histrank<<<gE, B, 0, stream>>>(ei, cnt_p, rank);
  k_scanA<<<gN, 256, 0, stream>>>(cnt_p, rs, bsum);
  k_scanB<<<1, 256, 0, stream>>>(bsum, boff);
  k_scanC<<<gN, B, 0, stream>>>(rs, boff);
  k_place<<<gE, B, 0, stream>>>(ei, ew, ea, rank, rs, rec, scal);
  k_deg<<<gN, B, 0, stream>>>((const uint_t*)rec, rs, dinv, scal);

  const float* xin = x;
  for (int l = 0; l < 2; ++l) {
    float* xout = (l == 0) ? xmid : (float*)d_out;
    k_dual_gemm<<<gMF, B, 0, stream>>>(xin, P[l][0], P[l][2], P[l][3], h16, resb);
    k_gcn_agg<<<gNW, B, 0, stream>>>(h16, resb, dinv, rs, (const uint_t*)rec,
                                     P[l][1], P[l][4], P[l][5], x2b, NN);
    k_gat_node<<<gMF, B, 0, stream>>>(x2b, P[l][6], P[l][8], P[l][9],
                                      P[l][11], P[l][10], xl16, asb, adb, wea);
    k_gat_agg<<<gNW, B, 0, stream>>>(xl16, x2b, asb, adb, rs, (const uint_t*)rec,
                                     wea, scal, P[l][7], xout, NN);
    xin = xout;
  }
}